// Round 6
// baseline (1616.004 us; speedup 1.0000x reference)
//
#include <hip/hip_runtime.h>
#include <hip/hip_bf16.h>
#include <math.h>

typedef __bf16 bf16_t;
typedef __bf16 bf16x8 __attribute__((ext_vector_type(8)));
typedef __bf16 bf16x4 __attribute__((ext_vector_type(4)));
typedef float f32x4 __attribute__((ext_vector_type(4)));

// async global->LDS, 16B per lane (linear LDS dest = wave base + lane*16)
__device__ __forceinline__ void gload16(const void* g, void* l)
{
    __builtin_amdgcn_global_load_lds(
        (const __attribute__((address_space(1))) void*)g,
        (__attribute__((address_space(3))) void*)l, 16, 0, 0);
}

// ---------------- np-exact f32 GEMM (encoder), v3 ----------------
// Round 15: A reads go DIRECT from global (L1/L2-broadcast), only B is
// LDS-staged. Rationale (round-5 PMC): 16 ds_read_b128 per kc per thread
// fed 256 FMAs -> LDS pipe demand 1536 cyc/CU vs VALU wall 1024 -> LDS-bound
// at 67% VALUBusy (measured 68%). A-side reads have only 4 distinct
// addresses per wave (ty-quads) and the A k-slice is 16KB (L1-resident;
// panel L2-local thanks to the round-5 XCD axis swap) -> moving A to direct
// global reads halves LDS demand (768 < 1024 -> VALU-bound) and removes the
// A-staging loop + 16KB LDS. Numerics bit-exact: same values, same
// ascending-k __fmaf_rn chain; skipped pad-k FMAs are fma(0,*)=no-ops.
// B staging unchanged: gload_lds width-16, XOR-swizzled source.
template<int ACT, int CB>   // ACT: 0 none, 1 relu;  BN = CB*64
__global__ __launch_bounds__(256)
void np_gemm3(const float* __restrict__ A, const float* __restrict__ W,
              const float* __restrict__ bias, float* __restrict__ C,
              int N, int Cstride, int KP, int KA, int Kreal)
{
    __shared__ __align__(16) float sB[CB * 64 * 32];
    const int tid = threadIdx.x;
    const int tx  = tid & 15, ty = tid >> 4;
    const int bRow = blockIdx.x * 128, bCol = blockIdx.y * (CB * 64);

    float acc[8][CB * 4];
#pragma unroll
    for (int i = 0; i < 8; ++i)
#pragma unroll
        for (int j = 0; j < CB * 4; ++j) acc[i][j] = 0.f;

    const int bswz = tx & 7;   // (brow>>2)&7 == tx&7 for brow=jb*64+tx*4+j

    // per-thread A row pointers (8 rows: ib*64 + ty*4 + i)
    const float* arow[8];
#pragma unroll
    for (int ib = 0; ib < 2; ++ib)
#pragma unroll
        for (int i = 0; i < 4; ++i)
            arow[ib * 4 + i] = A + (size_t)(bRow + ib * 64 + ty * 4 + i) * KA;

    for (int k0 = 0; k0 < KP; k0 += 32) {
        __syncthreads();
        // stage B tile (CB*64 rows x 32 k): pure async copy, source swizzled
#pragma unroll
        for (int i = 0; i < CB * 2; ++i) {
            int L = tid + i * 256;
            int r = L >> 3, cc = L & 7;
            int gc = cc ^ ((r >> 2) & 7);
            gload16(W + (size_t)(bCol + r) * KP + (k0 + gc * 4), sB + L * 4);
        }
        __syncthreads();

#pragma unroll
        for (int kc = 0; kc < 8; ++kc) {
            const int gk = k0 + kc * 4;
            const int bc = ((kc ^ bswz) << 2);
            float4 b4[CB][4];
#pragma unroll
            for (int jb = 0; jb < CB; ++jb)
#pragma unroll
                for (int j = 0; j < 4; ++j)
                    b4[jb][j] = *(const float4*)(sB + (jb * 64 + tx * 4 + j) * 32 + bc);
            if (gk < Kreal) {     // uniform; pad-k FMAs would be exact no-ops
#pragma unroll
                for (int r = 0; r < 8; ++r) {
                    float4 a4 = *(const float4*)(arow[r] + gk);
#pragma unroll
                    for (int jb = 0; jb < CB; ++jb)
#pragma unroll
                        for (int j = 0; j < 4; ++j) {
                            float& o = acc[r][jb * 4 + j];
                            o = __fmaf_rn(a4.x, b4[jb][j].x, o);
                            o = __fmaf_rn(a4.y, b4[jb][j].y, o);
                            o = __fmaf_rn(a4.z, b4[jb][j].z, o);
                            o = __fmaf_rn(a4.w, b4[jb][j].w, o);
                        }
                }
            }
        }
    }

#pragma unroll
    for (int jb = 0; jb < CB; ++jb) {
        int col4 = bCol + jb * 64 + tx * 4;
        if (col4 >= Cstride) continue;     // Cstride%4==0 -> whole float4 ok
#pragma unroll
        for (int ib = 0; ib < 2; ++ib)
#pragma unroll
            for (int i = 0; i < 4; ++i) {
                int row = bRow + ib * 64 + ty * 4 + i;
                float ov[4];
#pragma unroll
                for (int j = 0; j < 4; ++j) {
                    int col = col4 + j;
                    float v = 0.f;
                    if (col < N) {
                        v = __fadd_rn(acc[ib * 4 + i][jb * 4 + j], bias[col]);
                        if (ACT == 1) v = v > 0.f ? v : 0.f;
                    }
                    ov[j] = v;
                }
                *(float4*)(C + (size_t)row * Cstride + col4) =
                    make_float4(ov[0], ov[1], ov[2], ov[3]);
            }
    }
}

// pad f32 matrix [rows][K] -> [rowsP][Kp] with zeros (encoder weights)
__global__ void k_padw(const float* __restrict__ src, float* __restrict__ dst,
                       int rows, int K, int rowsP, int Kp)
{
    int e = blockIdx.x * 256 + threadIdx.x;
    if (e >= rowsP * Kp) return;
    int r = e / Kp, k = e - r * Kp;
    dst[e] = (r < rows && k < K) ? src[(size_t)r * K + k] : 0.f;
}

// ---------------- split helper: f32 -> (bf16 hi, bf16 lo) planes ----------
__global__ void k_split(const float* __restrict__ src, bf16_t* __restrict__ hi,
                        bf16_t* __restrict__ lo, int rows, int K, int rowsP, int Kp)
{
    int e = blockIdx.x * 256 + threadIdx.x;
    if (e >= rowsP * Kp) return;
    int r = e / Kp, k = e - r * Kp;
    float v = (r < rows && k < K) ? src[(size_t)r * K + k] : 0.f;
    bf16_t h = (bf16_t)v;
    bf16_t l = (bf16_t)(v - (float)h);
    hi[e] = h; lo[e] = l;
}

// ---------------- bf16 MFMA GEMM on pre-split planes (decoder) ------------
template<int ACT, int OUT>
__global__ __launch_bounds__(256)
void gemm_planes(const bf16_t* __restrict__ Ahi, const bf16_t* __restrict__ Alo,
                 const bf16_t* __restrict__ Bhi, const bf16_t* __restrict__ Blo,
                 const float* __restrict__ bias,
                 float* __restrict__ C0, float* __restrict__ C1,
                 bf16_t* __restrict__ Phi, bf16_t* __restrict__ Plo,
                 int N, int Kp, int Kpn)
{
    __shared__ __align__(16) bf16_t sA[2][128][32];
    __shared__ __align__(16) bf16_t sB[2][128][32];

    const int tid  = threadIdx.x;
    const int bRow = blockIdx.x * 128;
    const int bCol = blockIdx.y * 128;
    const int wave = tid >> 6;
    const int lane = tid & 63;
    const int wr   = (wave >> 1) * 64;
    const int wc   = (wave & 1) * 64;
    const int quad = lane >> 4;
    const int l15  = lane & 15;

    f32x4 acc[4][4];
#pragma unroll
    for (int i = 0; i < 4; ++i)
#pragma unroll
        for (int j = 0; j < 4; ++j) acc[i][j] = (f32x4){0.f, 0.f, 0.f, 0.f};

    for (int k0 = 0; k0 < Kp; k0 += 32) {
        __syncthreads();
#pragma unroll
        for (int i = 0; i < 2; ++i) {
            int c    = tid + i * 256;
            int row  = c >> 2;
            int koff = (c & 3) << 3;
            size_t ga = (size_t)(bRow + row) * Kp + (k0 + koff);
            size_t gb = (size_t)(bCol + row) * Kp + (k0 + koff);
            gload16(Ahi + ga, &sA[0][row][koff]);
            gload16(Alo + ga, &sA[1][row][koff]);
            gload16(Bhi + gb, &sB[0][row][koff]);
            gload16(Blo + gb, &sB[1][row][koff]);
        }
        __syncthreads();

        bf16x8 af[2][4], bfr[2][4];
#pragma unroll
        for (int t = 0; t < 2; ++t)
#pragma unroll
            for (int i = 0; i < 4; ++i) {
                af[t][i]  = *(const bf16x8*)&sA[t][wr + i * 16 + l15][quad * 8];
                bfr[t][i] = *(const bf16x8*)&sB[t][wc + i * 16 + l15][quad * 8];
            }
#pragma unroll
        for (int i = 0; i < 4; ++i)
#pragma unroll
            for (int j = 0; j < 4; ++j)
#pragma unroll
                for (int ta = 0; ta < 2; ++ta)
#pragma unroll
                    for (int tb = 0; tb < 2 - ta; ++tb)
                        acc[i][j] = __builtin_amdgcn_mfma_f32_16x16x32_bf16(
                            af[ta][i], bfr[tb][j], acc[i][j], 0, 0, 0);
    }

#pragma unroll
    for (int j = 0; j < 4; ++j) {
        int col = bCol + wc + j * 16 + l15;
        if (OUT == 0) {
            if (col >= N) continue;
            float bv = bias[col];
#pragma unroll
            for (int i = 0; i < 4; ++i)
#pragma unroll
                for (int r = 0; r < 4; ++r) {
                    int row = bRow + wr + i * 16 + quad * 4 + r;
                    float v = acc[i][j][r] + bv;
                    if (ACT == 1)      v = v > 0.f ? v : 0.f;
                    else if (ACT == 2) v = v >= 0.f ? v : 0.1f * v;
                    else if (ACT == 3) v = tanhf(v);
                    size_t o = (size_t)row * N + col;
                    C0[o] = v;
                    if (C1) C1[o] = v;
                }
        } else {
            if (col >= Kpn) continue;
            const bool real = col < N;
            float bv = real ? bias[col] : 0.f;
#pragma unroll
            for (int i = 0; i < 4; ++i)
#pragma unroll
                for (int r = 0; r < 4; ++r) {
                    int row = bRow + wr + i * 16 + quad * 4 + r;
                    float v = 0.f;
                    if (real) {
                        v = acc[i][j][r] + bv;
                        if (ACT == 1)      v = v > 0.f ? v : 0.f;
                        else if (ACT == 2) v = v >= 0.f ? v : 0.1f * v;
                        else if (ACT == 3) v = tanhf(v);
                    }
                    bf16_t h = (bf16_t)v;
                    bf16_t l = (bf16_t)(v - (float)h);
                    size_t o = (size_t)row * Kpn + col;
                    Phi[o] = h; Plo[o] = l;
                }
        }
    }
}

// np-exact nearest scan (bit-identical to np reference).
__global__ __launch_bounds__(256)
void k_nearest(const float* __restrict__ Q, const float* __restrict__ C,
               const float* __restrict__ q2a, const float* __restrict__ cn2,
               int chunk, float* __restrict__ pd, int* __restrict__ pi)
{
    __shared__ __align__(16) float sc[64][64];
    __shared__ __align__(16) float sn[64];
    const int tid = threadIdx.x;
    const int q   = blockIdx.x * 256 + tid;
    const int G   = gridDim.y;

    float qr[64];
    const float4* qp = (const float4*)(Q + (size_t)q * 64);
#pragma unroll
    for (int i = 0; i < 16; ++i) ((float4*)qr)[i] = qp[i];
    const float q2 = q2a[q];

    float best = 3.4e38f;
    int   bi   = 0x7fffffff;
    const int c0 = blockIdx.y * chunk;

    for (int cb = 0; cb < chunk; cb += 64) {
        __syncthreads();
        const float4* gp = (const float4*)(C + (size_t)(c0 + cb) * 64);
#pragma unroll
        for (int i = 0; i < 4; ++i) {
            int e = tid + i * 256;
            ((float4*)&sc[0][0])[e] = gp[e];
        }
        if (tid < 64) sn[tid] = cn2[c0 + cb + tid];
        __syncthreads();

        for (int c = 0; c < 64; c += 4) {
            float a0 = 0.f, a1 = 0.f, a2 = 0.f, a3 = 0.f;
            const float4* e0 = (const float4*)&sc[c + 0][0];
            const float4* e1 = (const float4*)&sc[c + 1][0];
            const float4* e2p = (const float4*)&sc[c + 2][0];
            const float4* e3 = (const float4*)&sc[c + 3][0];
#pragma unroll
            for (int z = 0; z < 16; ++z) {          // k ascending, chain order exact
                float4 q4 = ((float4*)qr)[z];
                float4 v0 = e0[z], v1 = e1[z], v2 = e2p[z], v3 = e3[z];
                a0 = __fmaf_rn(q4.x, v0.x, a0); a0 = __fmaf_rn(q4.y, v0.y, a0);
                a0 = __fmaf_rn(q4.z, v0.z, a0); a0 = __fmaf_rn(q4.w, v0.w, a0);
                a1 = __fmaf_rn(q4.x, v1.x, a1); a1 = __fmaf_rn(q4.y, v1.y, a1);
                a1 = __fmaf_rn(q4.z, v1.z, a1); a1 = __fmaf_rn(q4.w, v1.w, a1);
                a2 = __fmaf_rn(q4.x, v2.x, a2); a2 = __fmaf_rn(q4.y, v2.y, a2);
                a2 = __fmaf_rn(q4.z, v2.z, a2); a2 = __fmaf_rn(q4.w, v2.w, a2);
                a3 = __fmaf_rn(q4.x, v3.x, a3); a3 = __fmaf_rn(q4.y, v3.y, a3);
                a3 = __fmaf_rn(q4.z, v3.z, a3); a3 = __fmaf_rn(q4.w, v3.w, a3);
            }
            float d;
            d = __fadd_rn(__fsub_rn(q2, __fmul_rn(2.f, a0)), sn[c + 0]);
            if (d < best) { best = d; bi = c0 + cb + c + 0; }
            d = __fadd_rn(__fsub_rn(q2, __fmul_rn(2.f, a1)), sn[c + 1]);
            if (d < best) { best = d; bi = c0 + cb + c + 1; }
            d = __fadd_rn(__fsub_rn(q2, __fmul_rn(2.f, a2)), sn[c + 2]);
            if (d < best) { best = d; bi = c0 + cb + c + 2; }
            d = __fadd_rn(__fsub_rn(q2, __fmul_rn(2.f, a3)), sn[c + 3]);
            if (d < best) { best = d; bi = c0 + cb + c + 3; }
        }
    }
    pd[(size_t)q * G + blockIdx.y] = best;
    pi[(size_t)q * G + blockIdx.y] = bi;
}

__global__ void k_reduce(const float* __restrict__ pd, const int* __restrict__ pi,
                         int G, int NQ, int* __restrict__ out)
{
    int q = blockIdx.x * blockDim.x + threadIdx.x;
    if (q >= NQ) return;
    float best = 3.4e38f; int bi = 0;
    for (int g = 0; g < G; ++g) {
        float d = pd[(size_t)q * G + g];
        if (d < best) { best = d; bi = pi[(size_t)q * G + g]; }
    }
    out[q] = bi;
}

__global__ void k_gather(const float* __restrict__ src, const int* __restrict__ idx,
                         float* __restrict__ dst, int nsrc)
{
    int r = blockIdx.x, z = threadIdx.x;
    int i = idx[r];
    i = i < 0 ? 0 : (i >= nsrc ? nsrc - 1 : i);
    dst[(size_t)r * 64 + z] = src[(size_t)i * 64 + z];
}

// gather emb rows -> split bf16 planes (decoder layer-1 A input).
__global__ void k_gather_split(const float* __restrict__ src, const int* __restrict__ idx,
                               bf16_t* __restrict__ hi, bf16_t* __restrict__ lo, int nsrc)
{
    int r = blockIdx.x, z = threadIdx.x;
    int i = idx[r];
    i = i < 0 ? 0 : (i >= nsrc ? nsrc - 1 : i);
    float v = src[(size_t)i * 64 + z];
    bf16_t h = (bf16_t)v;
    bf16_t l = (bf16_t)(v - (float)h);
    hi[(size_t)r * 64 + z] = h;
    lo[(size_t)r * 64 + z] = l;
}

// numpy pairwise row norm^2 (n=64), bit-exact.
__global__ void k_norm2(const float* __restrict__ s, float* __restrict__ o, int rows)
{
    int r0 = blockIdx.x * blockDim.x + threadIdx.x;
    if (r0 >= rows) return;
    const float* p = s + (size_t)r0 * 64;
    float r[8];
#pragma unroll
    for (int j = 0; j < 8; ++j) r[j] = __fmul_rn(p[j], p[j]);
#pragma unroll
    for (int i = 8; i < 64; i += 8)
#pragma unroll
        for (int j = 0; j < 8; ++j)
            r[j] = __fadd_rn(r[j], __fmul_rn(p[i + j], p[i + j]));
    float t01 = __fadd_rn(r[0], r[1]), t23 = __fadd_rn(r[2], r[3]);
    float t45 = __fadd_rn(r[4], r[5]), t67 = __fadd_rn(r[6], r[7]);
    o[r0] = __fadd_rn(__fadd_rn(t01, t23), __fadd_rn(t45, t67));
}

extern "C" void kernel_launch(void* const* d_in, const int* in_sizes, int n_in,
                              void* d_out, int out_size, void* d_ws, size_t ws_size,
                              hipStream_t stream)
{
    const int B  = 16384;
    const int KC = 4096;

    const float* X   = (const float*)d_in[0];
    const float* We1 = (const float*)d_in[1];
    const float* be1 = (const float*)d_in[2];
    const float* We2 = (const float*)d_in[3];
    const float* be2 = (const float*)d_in[4];
    const float* We3 = (const float*)d_in[5];
    const float* be3 = (const float*)d_in[6];
    const float* We4 = (const float*)d_in[7];
    const float* be4 = (const float*)d_in[8];
    const float* emb = (const float*)d_in[9];
    const float* Wd1 = (const float*)d_in[10];
    const float* bd1 = (const float*)d_in[11];
    const float* Wd2 = (const float*)d_in[12];
    const float* bd2 = (const float*)d_in[13];
    const float* Wd3 = (const float*)d_in[14];
    const float* bd3 = (const float*)d_in[15];
    const float* Wd4 = (const float*)d_in[16];
    const float* bd4 = (const float*)d_in[17];

    float* out = (float*)d_out;
    const size_t OFF1 = (size_t)B * 784;
    const size_t OFF2 = OFF1 + (size_t)B * 64;
    const size_t OFF3 = OFF2 + (size_t)B * 784;
    float* zenc = out + OFF1;

    // dynamic batch tiling (ws_size constant across calls -> graph-safe).
    const size_t FIXED = (size_t)24 << 20;
    int MQ;
    if      (ws_size >= FIXED + (size_t)16384 * 7424) MQ = 16384;
    else if (ws_size >= FIXED + (size_t)8192  * 7424) MQ = 8192;
    else                                              MQ = 4096;
    const int NQn = B / MQ;

    char* ws = (char*)d_ws;
    size_t off = 0;
    auto alloc = [&](size_t bytes) -> void* {
        void* p = ws + off;
        off = (off + bytes + 255) & ~(size_t)255;
        return p;
    };
    float* pd    = (float*)alloc((size_t)262144 * 4);
    int*   pi    = (int*)alloc((size_t)262144 * 4);
    int*   idx1  = (int*)alloc((size_t)B * 4);
    int*   idx2  = (int*)alloc((size_t)KC * 4);
    float* e2    = (float*)alloc((size_t)KC * 4);
    float* z2    = (float*)alloc((size_t)B * 4);
    // encoder padded weights (f32, [NP][KP] zeros)
    float* we1p = (float*)alloc((size_t)1024 * 800 * 4);
    float* we2p = (float*)alloc((size_t)512 * 1024 * 4);
    float* we3p = (float*)alloc((size_t)384 * 512 * 4);
    float* we4p = (float*)alloc((size_t)128 * 320 * 4);
    // decoder split bf16 planes: zemb (full B) + weights
    bf16_t* zembh = (bf16_t*)alloc((size_t)B * 64 * 2);
    bf16_t* zembl = (bf16_t*)alloc((size_t)B * 64 * 2);
    bf16_t* wp1h = (bf16_t*)alloc((size_t)384 * 64 * 2);
    bf16_t* wp1l = (bf16_t*)alloc((size_t)384 * 64 * 2);
    bf16_t* wp2h = (bf16_t*)alloc((size_t)512 * 320 * 2);
    bf16_t* wp2l = (bf16_t*)alloc((size_t)512 * 320 * 2);
    bf16_t* wp3h = (bf16_t*)alloc((size_t)1024 * 512 * 2);
    bf16_t* wp3l = (bf16_t*)alloc((size_t)1024 * 512 * 2);
    bf16_t* wp4h = (bf16_t*)alloc((size_t)896 * 1024 * 2);
    bf16_t* wp4l = (bf16_t*)alloc((size_t)896 * 1024 * 2);
    // big shared region: encoder padded f32 h1..h3, then decoder act planes
    char* big = (char*)alloc((size_t)MQ * 7424);
    float* h1 = (float*)big;                           // MQ x 1024 f32 (N=1000)
    float* h2 = (float*)(big + (size_t)MQ * 4096);     // MQ x 512  (N=500)
    float* h3 = (float*)(big + (size_t)MQ * 6144);     // MQ x 320  (N=300)
    bf16_t* d1h = (bf16_t*)big;                        // MQ x 320 bf16
    bf16_t* d1l = (bf16_t*)(big + (size_t)MQ * 640);
    bf16_t* d2h = (bf16_t*)(big + (size_t)MQ * 1280);  // MQ x 512
    bf16_t* d2l = (bf16_t*)(big + (size_t)MQ * 2304);
    bf16_t* d3h = (bf16_t*)(big + (size_t)MQ * 3328);  // MQ x 1024
    bf16_t* d3l = (bf16_t*)(big + (size_t)MQ * 5376);

    dim3 blk(256);
    // encoder grids: x = row-panels (XCD locality), y = col-blocks.
    // y sized to Cstride/BN exactly (round-4 had 2 fully-wasted columns).
    const dim3 eg1(MQ / 128, 8), eg2(MQ / 128, 8), eg3(MQ / 128, 5), eg4(MQ / 128, 1);
    // decoder grids: same axis order
    const dim3 dq1(MQ / 128, 3), dq2(MQ / 128, 4), dq3(MQ / 128, 8), dq4(MQ / 128, 7);

    // ---- weight pre-pad / pre-split (tiny, input-only dependency) ----
    k_padw<<<dim3((1024 * 800 + 255) / 256), blk, 0, stream>>>(We1, we1p, 1000, 784, 1024, 800);
    k_padw<<<dim3((512 * 1024 + 255) / 256), blk, 0, stream>>>(We2, we2p, 500, 1000, 512, 1024);
    k_padw<<<dim3((384 * 512  + 255) / 256), blk, 0, stream>>>(We3, we3p, 300, 500, 384, 512);
    k_padw<<<dim3((128 * 320  + 255) / 256), blk, 0, stream>>>(We4, we4p, 64, 300, 128, 320);
    k_split<<<dim3((384 * 64   + 255) / 256), blk, 0, stream>>>(Wd1, wp1h, wp1l, 300, 64, 384, 64);
    k_split<<<dim3((512 * 320  + 255) / 256), blk, 0, stream>>>(Wd2, wp2h, wp2l, 500, 300, 512, 320);
    k_split<<<dim3((1024 * 512 + 255) / 256), blk, 0, stream>>>(Wd3, wp3h, wp3l, 1000, 500, 1024, 512);
    k_split<<<dim3((896 * 1024 + 255) / 256), blk, 0, stream>>>(Wd4, wp4h, wp4l, 784, 1000, 896, 1024);

    // ---- encoder, np-exact f32 (BLAS-order FMA chains) ----
    for (int q = 0; q < NQn; ++q) {
        const float* Xq = X + (size_t)q * MQ * 784;
        np_gemm3<1, 2><<<eg1, blk, 0, stream>>>(Xq, we1p, be1, h1, 1000, 1024, 800, 784, 784);
        np_gemm3<1, 1><<<eg2, blk, 0, stream>>>(h1, we2p, be2, h2, 500, 512, 1024, 1024, 1024);
        np_gemm3<1, 1><<<eg3, blk, 0, stream>>>(h2, we3p, be3, h3, 300, 320, 512, 512, 512);
        np_gemm3<0, 1><<<eg4, blk, 0, stream>>>(h3, we4p, be4,
                                                zenc + (size_t)q * MQ * 64, 64, 64, 320, 320, 320);
    }

    // ---- nearest-neighbor: np-exact, no refine ----
    k_norm2<<<dim3((KC + 255) / 256), blk, 0, stream>>>(emb, e2, KC);
    k_norm2<<<dim3((B + 255) / 256),  blk, 0, stream>>>(zenc, z2, B);

    k_nearest<<<dim3(64, 16), blk, 0, stream>>>(zenc, emb, z2, e2, 256, pd, pi);
    k_reduce <<<dim3(B / 256), blk, 0, stream>>>(pd, pi, 16, B, idx1);
    k_gather_split<<<dim3(B), dim3(64), 0, stream>>>(emb, idx1, zembh, zembl, KC);

    k_nearest<<<dim3(16, 64), blk, 0, stream>>>(emb, zenc, e2, z2, 256, pd, pi);
    k_reduce <<<dim3(KC / 256), blk, 0, stream>>>(pd, pi, 64, KC, idx2);
    k_gather <<<dim3(KC), dim3(64), 0, stream>>>(zenc, idx2, out + OFF3, B);

    // ---- decoder: pre-split planes + global_load_lds MFMA GEMM ----
    for (int q = 0; q < NQn; ++q) {
        gemm_planes<2, 1><<<dq1, blk, 0, stream>>>(
            zembh + (size_t)q * MQ * 64, zembl + (size_t)q * MQ * 64,
            wp1h, wp1l, bd1, nullptr, nullptr, d1h, d1l, 300, 64, 320);
        gemm_planes<2, 1><<<dq2, blk, 0, stream>>>(
            d1h, d1l, wp2h, wp2l, bd2, nullptr, nullptr, d2h, d2l, 500, 320, 512);
        gemm_planes<2, 1><<<dq3, blk, 0, stream>>>(
            d2h, d2l, wp3h, wp3l, bd3, nullptr, nullptr, d3h, d3l, 1000, 512, 1024);
        gemm_planes<3, 0><<<dq4, blk, 0, stream>>>(
            d3h, d3l, wp4h, wp4l, bd4,
            out + (size_t)q * MQ * 784, out + OFF2 + (size_t)q * MQ * 784,
            nullptr, nullptr, 784, 1024, 0);
    }

    (void)in_sizes; (void)n_in; (void)out_size;
}

// Round 7
// 1543.440 us; speedup vs baseline: 1.0470x; 1.0470x over previous
//
#include <hip/hip_runtime.h>
#include <hip/hip_bf16.h>
#include <math.h>

typedef __bf16 bf16_t;
typedef __bf16 bf16x8 __attribute__((ext_vector_type(8)));
typedef __bf16 bf16x4 __attribute__((ext_vector_type(4)));
typedef float f32x4 __attribute__((ext_vector_type(4)));

// async global->LDS, 16B per lane (linear LDS dest = wave base + lane*16)
__device__ __forceinline__ void gload16(const void* g, void* l)
{
    __builtin_amdgcn_global_load_lds(
        (const __attribute__((address_space(1))) void*)g,
        (__attribute__((address_space(3))) void*)l, 16, 0, 0);
}

// ---------------- np-exact f32 GEMM (encoder), v4 ----------------
// Round 16: back to r5's both-operands-staged structure (A-direct r6
// regressed: VMEM latency exposed at 2 blocks/CU; conflicts unchanged ->
// LDS reads of B were never the A-side's fault). New lever: BIGGER
// per-thread tile to cut LDS instructions per FMA (r5 model: LDS wall
// 1536 cyc vs VALU wall 1024 per 8-wave round = LDS-bound at 67%, measured
// 68%). RB=4 -> 16x8 per thread: 24 b128 reads / 512 FMAs (vs 16/256) =
// 25% less LDS demand per FLOP. Swizzle algebra unchanged (aswz=ty&7,
// bswz=tx&7 are RB-independent). Zero-filled A edge staging + zero-padded
// W let the pad-k FMAs run as exact fma(0,0,acc) no-ops -> no k guard.
// Numerics bit-exact: same values, same ascending-k __fmaf_rn chains.
template<int ACT, int RB, int CB>   // BM = RB*64, BN = CB*64
__global__ __launch_bounds__(256)
void np_gemm4(const float* __restrict__ A, const float* __restrict__ W,
              const float* __restrict__ bias, float* __restrict__ C,
              int N, int Cstride, int KP, int KA, int Kreal)
{
    __shared__ __align__(16) float sA[RB * 64 * 32];
    __shared__ __align__(16) float sB[CB * 64 * 32];
    const int tid = threadIdx.x;
    const int tx  = tid & 15, ty = tid >> 4;
    const int bRow = blockIdx.x * (RB * 64), bCol = blockIdx.y * (CB * 64);

    float acc[RB * 4][CB * 4];
#pragma unroll
    for (int i = 0; i < RB * 4; ++i)
#pragma unroll
        for (int j = 0; j < CB * 4; ++j) acc[i][j] = 0.f;

    const int aswz = ty & 7;   // (arow>>2)&7 == ty&7 (arow = ib*64+ty*4+i)
    const int bswz = tx & 7;   // (brow>>2)&7 == tx&7 (brow = jb*64+tx*4+j)

    for (int k0 = 0; k0 < KP; k0 += 32) {
        __syncthreads();
        if (k0 + 32 <= Kreal) {
            // full tile: pure async copy, source pre-swizzled
#pragma unroll
            for (int i = 0; i < RB * 2; ++i) {
                int L = tid + i * 256;
                int r = L >> 3, cc = L & 7;
                int gc = cc ^ ((r >> 2) & 7);
                gload16(A + (size_t)(bRow + r) * KA + (k0 + gc * 4), sA + L * 4);
            }
        } else {
            // layer-1 K edge (k0=768, Kreal=784): predicated reg staging,
            // zero fill -> pad FMAs are exact no-ops (W pad is zero too)
#pragma unroll
            for (int i = 0; i < RB * 2; ++i) {
                int L = tid + i * 256;
                int r = L >> 3, cc = L & 7;
                int gc = cc ^ ((r >> 2) & 7);
                int gk = k0 + gc * 4;
                float4 v = make_float4(0.f, 0.f, 0.f, 0.f);
                if (gk < Kreal) v = *(const float4*)(A + (size_t)(bRow + r) * KA + gk);
                *(float4*)(sA + L * 4) = v;
            }
        }
#pragma unroll
        for (int i = 0; i < CB * 2; ++i) {
            int L = tid + i * 256;
            int r = L >> 3, cc = L & 7;
            int gc = cc ^ ((r >> 2) & 7);
            gload16(W + (size_t)(bCol + r) * KP + (k0 + gc * 4), sB + L * 4);
        }
        __syncthreads();

#pragma unroll
        for (int kc = 0; kc < 8; ++kc) {       // strictly ascending k
            const int ac = ((kc ^ aswz) << 2);
            const int bc = ((kc ^ bswz) << 2);
            float4 b4[CB][4];
#pragma unroll
            for (int jb = 0; jb < CB; ++jb)
#pragma unroll
                for (int j = 0; j < 4; ++j)
                    b4[jb][j] = *(const float4*)(sB + (jb * 64 + tx * 4 + j) * 32 + bc);
#pragma unroll
            for (int ib = 0; ib < RB; ++ib)
#pragma unroll
                for (int i = 0; i < 4; ++i) {
                    float4 a4 = *(const float4*)(sA + (ib * 64 + ty * 4 + i) * 32 + ac);
#pragma unroll
                    for (int jb = 0; jb < CB; ++jb)
#pragma unroll
                        for (int j = 0; j < 4; ++j) {
                            float& o = acc[ib * 4 + i][jb * 4 + j];
                            o = __fmaf_rn(a4.x, b4[jb][j].x, o);
                            o = __fmaf_rn(a4.y, b4[jb][j].y, o);
                            o = __fmaf_rn(a4.z, b4[jb][j].z, o);
                            o = __fmaf_rn(a4.w, b4[jb][j].w, o);
                        }
                }
        }
    }

#pragma unroll
    for (int jb = 0; jb < CB; ++jb) {
        int col4 = bCol + jb * 64 + tx * 4;
        if (col4 >= Cstride) continue;     // Cstride%4==0 -> whole float4 ok
#pragma unroll
        for (int ib = 0; ib < RB; ++ib)
#pragma unroll
            for (int i = 0; i < 4; ++i) {
                int row = bRow + ib * 64 + ty * 4 + i;
                float ov[4];
#pragma unroll
                for (int j = 0; j < 4; ++j) {
                    int col = col4 + j;
                    float v = 0.f;
                    if (col < N) {
                        v = __fadd_rn(acc[ib * 4 + i][jb * 4 + j], bias[col]);
                        if (ACT == 1) v = v > 0.f ? v : 0.f;
                    }
                    ov[j] = v;
                }
                *(float4*)(C + (size_t)row * Cstride + col4) =
                    make_float4(ov[0], ov[1], ov[2], ov[3]);
            }
    }
}

// pad f32 matrix [rows][K] -> [rowsP][Kp] with zeros (encoder weights)
__global__ void k_padw(const float* __restrict__ src, float* __restrict__ dst,
                       int rows, int K, int rowsP, int Kp)
{
    int e = blockIdx.x * 256 + threadIdx.x;
    if (e >= rowsP * Kp) return;
    int r = e / Kp, k = e - r * Kp;
    dst[e] = (r < rows && k < K) ? src[(size_t)r * K + k] : 0.f;
}

// ---------------- split helper: f32 -> (bf16 hi, bf16 lo) planes ----------
__global__ void k_split(const float* __restrict__ src, bf16_t* __restrict__ hi,
                        bf16_t* __restrict__ lo, int rows, int K, int rowsP, int Kp)
{
    int e = blockIdx.x * 256 + threadIdx.x;
    if (e >= rowsP * Kp) return;
    int r = e / Kp, k = e - r * Kp;
    float v = (r < rows && k < K) ? src[(size_t)r * K + k] : 0.f;
    bf16_t h = (bf16_t)v;
    bf16_t l = (bf16_t)(v - (float)h);
    hi[e] = h; lo[e] = l;
}

// ---------------- bf16 MFMA GEMM on pre-split planes (decoder) ------------
template<int ACT, int OUT>
__global__ __launch_bounds__(256)
void gemm_planes(const bf16_t* __restrict__ Ahi, const bf16_t* __restrict__ Alo,
                 const bf16_t* __restrict__ Bhi, const bf16_t* __restrict__ Blo,
                 const float* __restrict__ bias,
                 float* __restrict__ C0, float* __restrict__ C1,
                 bf16_t* __restrict__ Phi, bf16_t* __restrict__ Plo,
                 int N, int Kp, int Kpn)
{
    __shared__ __align__(16) bf16_t sA[2][128][32];
    __shared__ __align__(16) bf16_t sB[2][128][32];

    const int tid  = threadIdx.x;
    const int bRow = blockIdx.x * 128;
    const int bCol = blockIdx.y * 128;
    const int wave = tid >> 6;
    const int lane = tid & 63;
    const int wr   = (wave >> 1) * 64;
    const int wc   = (wave & 1) * 64;
    const int quad = lane >> 4;
    const int l15  = lane & 15;

    f32x4 acc[4][4];
#pragma unroll
    for (int i = 0; i < 4; ++i)
#pragma unroll
        for (int j = 0; j < 4; ++j) acc[i][j] = (f32x4){0.f, 0.f, 0.f, 0.f};

    for (int k0 = 0; k0 < Kp; k0 += 32) {
        __syncthreads();
#pragma unroll
        for (int i = 0; i < 2; ++i) {
            int c    = tid + i * 256;
            int row  = c >> 2;
            int koff = (c & 3) << 3;
            size_t ga = (size_t)(bRow + row) * Kp + (k0 + koff);
            size_t gb = (size_t)(bCol + row) * Kp + (k0 + koff);
            gload16(Ahi + ga, &sA[0][row][koff]);
            gload16(Alo + ga, &sA[1][row][koff]);
            gload16(Bhi + gb, &sB[0][row][koff]);
            gload16(Blo + gb, &sB[1][row][koff]);
        }
        __syncthreads();

        bf16x8 af[2][4], bfr[2][4];
#pragma unroll
        for (int t = 0; t < 2; ++t)
#pragma unroll
            for (int i = 0; i < 4; ++i) {
                af[t][i]  = *(const bf16x8*)&sA[t][wr + i * 16 + l15][quad * 8];
                bfr[t][i] = *(const bf16x8*)&sB[t][wc + i * 16 + l15][quad * 8];
            }
#pragma unroll
        for (int i = 0; i < 4; ++i)
#pragma unroll
            for (int j = 0; j < 4; ++j)
#pragma unroll
                for (int ta = 0; ta < 2; ++ta)
#pragma unroll
                    for (int tb = 0; tb < 2 - ta; ++tb)
                        acc[i][j] = __builtin_amdgcn_mfma_f32_16x16x32_bf16(
                            af[ta][i], bfr[tb][j], acc[i][j], 0, 0, 0);
    }

#pragma unroll
    for (int j = 0; j < 4; ++j) {
        int col = bCol + wc + j * 16 + l15;
        if (OUT == 0) {
            if (col >= N) continue;
            float bv = bias[col];
#pragma unroll
            for (int i = 0; i < 4; ++i)
#pragma unroll
                for (int r = 0; r < 4; ++r) {
                    int row = bRow + wr + i * 16 + quad * 4 + r;
                    float v = acc[i][j][r] + bv;
                    if (ACT == 1)      v = v > 0.f ? v : 0.f;
                    else if (ACT == 2) v = v >= 0.f ? v : 0.1f * v;
                    else if (ACT == 3) v = tanhf(v);
                    size_t o = (size_t)row * N + col;
                    C0[o] = v;
                    if (C1) C1[o] = v;
                }
        } else {
            if (col >= Kpn) continue;
            const bool real = col < N;
            float bv = real ? bias[col] : 0.f;
#pragma unroll
            for (int i = 0; i < 4; ++i)
#pragma unroll
                for (int r = 0; r < 4; ++r) {
                    int row = bRow + wr + i * 16 + quad * 4 + r;
                    float v = 0.f;
                    if (real) {
                        v = acc[i][j][r] + bv;
                        if (ACT == 1)      v = v > 0.f ? v : 0.f;
                        else if (ACT == 2) v = v >= 0.f ? v : 0.1f * v;
                        else if (ACT == 3) v = tanhf(v);
                    }
                    bf16_t h = (bf16_t)v;
                    bf16_t l = (bf16_t)(v - (float)h);
                    size_t o = (size_t)row * Kpn + col;
                    Phi[o] = h; Plo[o] = l;
                }
        }
    }
}

// np-exact nearest scan (bit-identical to np reference).
__global__ __launch_bounds__(256)
void k_nearest(const float* __restrict__ Q, const float* __restrict__ C,
               const float* __restrict__ q2a, const float* __restrict__ cn2,
               int chunk, float* __restrict__ pd, int* __restrict__ pi)
{
    __shared__ __align__(16) float sc[64][64];
    __shared__ __align__(16) float sn[64];
    const int tid = threadIdx.x;
    const int q   = blockIdx.x * 256 + tid;
    const int G   = gridDim.y;

    float qr[64];
    const float4* qp = (const float4*)(Q + (size_t)q * 64);
#pragma unroll
    for (int i = 0; i < 16; ++i) ((float4*)qr)[i] = qp[i];
    const float q2 = q2a[q];

    float best = 3.4e38f;
    int   bi   = 0x7fffffff;
    const int c0 = blockIdx.y * chunk;

    for (int cb = 0; cb < chunk; cb += 64) {
        __syncthreads();
        const float4* gp = (const float4*)(C + (size_t)(c0 + cb) * 64);
#pragma unroll
        for (int i = 0; i < 4; ++i) {
            int e = tid + i * 256;
            ((float4*)&sc[0][0])[e] = gp[e];
        }
        if (tid < 64) sn[tid] = cn2[c0 + cb + tid];
        __syncthreads();

        for (int c = 0; c < 64; c += 4) {
            float a0 = 0.f, a1 = 0.f, a2 = 0.f, a3 = 0.f;
            const float4* e0 = (const float4*)&sc[c + 0][0];
            const float4* e1 = (const float4*)&sc[c + 1][0];
            const float4* e2p = (const float4*)&sc[c + 2][0];
            const float4* e3 = (const float4*)&sc[c + 3][0];
#pragma unroll
            for (int z = 0; z < 16; ++z) {          // k ascending, chain order exact
                float4 q4 = ((float4*)qr)[z];
                float4 v0 = e0[z], v1 = e1[z], v2 = e2p[z], v3 = e3[z];
                a0 = __fmaf_rn(q4.x, v0.x, a0); a0 = __fmaf_rn(q4.y, v0.y, a0);
                a0 = __fmaf_rn(q4.z, v0.z, a0); a0 = __fmaf_rn(q4.w, v0.w, a0);
                a1 = __fmaf_rn(q4.x, v1.x, a1); a1 = __fmaf_rn(q4.y, v1.y, a1);
                a1 = __fmaf_rn(q4.z, v1.z, a1); a1 = __fmaf_rn(q4.w, v1.w, a1);
                a2 = __fmaf_rn(q4.x, v2.x, a2); a2 = __fmaf_rn(q4.y, v2.y, a2);
                a2 = __fmaf_rn(q4.z, v2.z, a2); a2 = __fmaf_rn(q4.w, v2.w, a2);
                a3 = __fmaf_rn(q4.x, v3.x, a3); a3 = __fmaf_rn(q4.y, v3.y, a3);
                a3 = __fmaf_rn(q4.z, v3.z, a3); a3 = __fmaf_rn(q4.w, v3.w, a3);
            }
            float d;
            d = __fadd_rn(__fsub_rn(q2, __fmul_rn(2.f, a0)), sn[c + 0]);
            if (d < best) { best = d; bi = c0 + cb + c + 0; }
            d = __fadd_rn(__fsub_rn(q2, __fmul_rn(2.f, a1)), sn[c + 1]);
            if (d < best) { best = d; bi = c0 + cb + c + 1; }
            d = __fadd_rn(__fsub_rn(q2, __fmul_rn(2.f, a2)), sn[c + 2]);
            if (d < best) { best = d; bi = c0 + cb + c + 2; }
            d = __fadd_rn(__fsub_rn(q2, __fmul_rn(2.f, a3)), sn[c + 3]);
            if (d < best) { best = d; bi = c0 + cb + c + 3; }
        }
    }
    pd[(size_t)q * G + blockIdx.y] = best;
    pi[(size_t)q * G + blockIdx.y] = bi;
}

__global__ void k_reduce(const float* __restrict__ pd, const int* __restrict__ pi,
                         int G, int NQ, int* __restrict__ out)
{
    int q = blockIdx.x * blockDim.x + threadIdx.x;
    if (q >= NQ) return;
    float best = 3.4e38f; int bi = 0;
    for (int g = 0; g < G; ++g) {
        float d = pd[(size_t)q * G + g];
        if (d < best) { best = d; bi = pi[(size_t)q * G + g]; }
    }
    out[q] = bi;
}

__global__ void k_gather(const float* __restrict__ src, const int* __restrict__ idx,
                         float* __restrict__ dst, int nsrc)
{
    int r = blockIdx.x, z = threadIdx.x;
    int i = idx[r];
    i = i < 0 ? 0 : (i >= nsrc ? nsrc - 1 : i);
    dst[(size_t)r * 64 + z] = src[(size_t)i * 64 + z];
}

// gather emb rows -> split bf16 planes (decoder layer-1 A input).
__global__ void k_gather_split(const float* __restrict__ src, const int* __restrict__ idx,
                               bf16_t* __restrict__ hi, bf16_t* __restrict__ lo, int nsrc)
{
    int r = blockIdx.x, z = threadIdx.x;
    int i = idx[r];
    i = i < 0 ? 0 : (i >= nsrc ? nsrc - 1 : i);
    float v = src[(size_t)i * 64 + z];
    bf16_t h = (bf16_t)v;
    bf16_t l = (bf16_t)(v - (float)h);
    hi[(size_t)r * 64 + z] = h;
    lo[(size_t)r * 64 + z] = l;
}

// numpy pairwise row norm^2 (n=64), bit-exact.
__global__ void k_norm2(const float* __restrict__ s, float* __restrict__ o, int rows)
{
    int r0 = blockIdx.x * blockDim.x + threadIdx.x;
    if (r0 >= rows) return;
    const float* p = s + (size_t)r0 * 64;
    float r[8];
#pragma unroll
    for (int j = 0; j < 8; ++j) r[j] = __fmul_rn(p[j], p[j]);
#pragma unroll
    for (int i = 8; i < 64; i += 8)
#pragma unroll
        for (int j = 0; j < 8; ++j)
            r[j] = __fadd_rn(r[j], __fmul_rn(p[i + j], p[i + j]));
    float t01 = __fadd_rn(r[0], r[1]), t23 = __fadd_rn(r[2], r[3]);
    float t45 = __fadd_rn(r[4], r[5]), t67 = __fadd_rn(r[6], r[7]);
    o[r0] = __fadd_rn(__fadd_rn(t01, t23), __fadd_rn(t45, t67));
}

extern "C" void kernel_launch(void* const* d_in, const int* in_sizes, int n_in,
                              void* d_out, int out_size, void* d_ws, size_t ws_size,
                              hipStream_t stream)
{
    const int B  = 16384;
    const int KC = 4096;

    const float* X   = (const float*)d_in[0];
    const float* We1 = (const float*)d_in[1];
    const float* be1 = (const float*)d_in[2];
    const float* We2 = (const float*)d_in[3];
    const float* be2 = (const float*)d_in[4];
    const float* We3 = (const float*)d_in[5];
    const float* be3 = (const float*)d_in[6];
    const float* We4 = (const float*)d_in[7];
    const float* be4 = (const float*)d_in[8];
    const float* emb = (const float*)d_in[9];
    const float* Wd1 = (const float*)d_in[10];
    const float* bd1 = (const float*)d_in[11];
    const float* Wd2 = (const float*)d_in[12];
    const float* bd2 = (const float*)d_in[13];
    const float* Wd3 = (const float*)d_in[14];
    const float* bd3 = (const float*)d_in[15];
    const float* Wd4 = (const float*)d_in[16];
    const float* bd4 = (const float*)d_in[17];

    float* out = (float*)d_out;
    const size_t OFF1 = (size_t)B * 784;
    const size_t OFF2 = OFF1 + (size_t)B * 64;
    const size_t OFF3 = OFF2 + (size_t)B * 784;
    float* zenc = out + OFF1;

    // dynamic batch tiling (ws_size constant across calls -> graph-safe).
    const size_t FIXED = (size_t)24 << 20;
    int MQ;
    if      (ws_size >= FIXED + (size_t)16384 * 7424) MQ = 16384;
    else if (ws_size >= FIXED + (size_t)8192  * 7424) MQ = 8192;
    else                                              MQ = 4096;
    const int NQn = B / MQ;

    char* ws = (char*)d_ws;
    size_t off = 0;
    auto alloc = [&](size_t bytes) -> void* {
        void* p = ws + off;
        off = (off + bytes + 255) & ~(size_t)255;
        return p;
    };
    float* pd    = (float*)alloc((size_t)262144 * 4);
    int*   pi    = (int*)alloc((size_t)262144 * 4);
    int*   idx1  = (int*)alloc((size_t)B * 4);
    int*   idx2  = (int*)alloc((size_t)KC * 4);
    float* e2    = (float*)alloc((size_t)KC * 4);
    float* z2    = (float*)alloc((size_t)B * 4);
    // encoder padded weights (f32, [NP][KP] zeros)
    float* we1p = (float*)alloc((size_t)1024 * 800 * 4);
    float* we2p = (float*)alloc((size_t)512 * 1024 * 4);
    float* we3p = (float*)alloc((size_t)384 * 512 * 4);
    float* we4p = (float*)alloc((size_t)128 * 320 * 4);
    // decoder split bf16 planes: zemb (full B) + weights
    bf16_t* zembh = (bf16_t*)alloc((size_t)B * 64 * 2);
    bf16_t* zembl = (bf16_t*)alloc((size_t)B * 64 * 2);
    bf16_t* wp1h = (bf16_t*)alloc((size_t)384 * 64 * 2);
    bf16_t* wp1l = (bf16_t*)alloc((size_t)384 * 64 * 2);
    bf16_t* wp2h = (bf16_t*)alloc((size_t)512 * 320 * 2);
    bf16_t* wp2l = (bf16_t*)alloc((size_t)512 * 320 * 2);
    bf16_t* wp3h = (bf16_t*)alloc((size_t)1024 * 512 * 2);
    bf16_t* wp3l = (bf16_t*)alloc((size_t)1024 * 512 * 2);
    bf16_t* wp4h = (bf16_t*)alloc((size_t)896 * 1024 * 2);
    bf16_t* wp4l = (bf16_t*)alloc((size_t)896 * 1024 * 2);
    // big shared region: encoder padded f32 h1..h3, then decoder act planes
    char* big = (char*)alloc((size_t)MQ * 7424);
    float* h1 = (float*)big;                           // MQ x 1024 f32 (N=1000)
    float* h2 = (float*)(big + (size_t)MQ * 4096);     // MQ x 512  (N=500)
    float* h3 = (float*)(big + (size_t)MQ * 6144);     // MQ x 320  (N=300)
    bf16_t* d1h = (bf16_t*)big;                        // MQ x 320 bf16
    bf16_t* d1l = (bf16_t*)(big + (size_t)MQ * 640);
    bf16_t* d2h = (bf16_t*)(big + (size_t)MQ * 1280);  // MQ x 512
    bf16_t* d2l = (bf16_t*)(big + (size_t)MQ * 2304);
    bf16_t* d3h = (bf16_t*)(big + (size_t)MQ * 3328);  // MQ x 1024
    bf16_t* d3l = (bf16_t*)(big + (size_t)MQ * 5376);

    dim3 blk(256);
    // encoder grids: x = row-panels (XCD locality), y = col-blocks
    // L1/L2: BM=256 (RB=4). L3: BM=128 (RB=2, BN=64, y=5). L4: BM=64.
    const dim3 eg1(MQ / 256, 8), eg2(MQ / 256, 4), eg3(MQ / 128, 5), eg4(MQ / 64, 1);
    // decoder grids: same axis order
    const dim3 dq1(MQ / 128, 3), dq2(MQ / 128, 4), dq3(MQ / 128, 8), dq4(MQ / 128, 7);

    // ---- weight pre-pad / pre-split (tiny, input-only dependency) ----
    k_padw<<<dim3((1024 * 800 + 255) / 256), blk, 0, stream>>>(We1, we1p, 1000, 784, 1024, 800);
    k_padw<<<dim3((512 * 1024 + 255) / 256), blk, 0, stream>>>(We2, we2p, 500, 1000, 512, 1024);
    k_padw<<<dim3((384 * 512  + 255) / 256), blk, 0, stream>>>(We3, we3p, 300, 500, 384, 512);
    k_padw<<<dim3((128 * 320  + 255) / 256), blk, 0, stream>>>(We4, we4p, 64, 300, 128, 320);
    k_split<<<dim3((384 * 64   + 255) / 256), blk, 0, stream>>>(Wd1, wp1h, wp1l, 300, 64, 384, 64);
    k_split<<<dim3((512 * 320  + 255) / 256), blk, 0, stream>>>(Wd2, wp2h, wp2l, 500, 300, 512, 320);
    k_split<<<dim3((1024 * 512 + 255) / 256), blk, 0, stream>>>(Wd3, wp3h, wp3l, 1000, 500, 1024, 512);
    k_split<<<dim3((896 * 1024 + 255) / 256), blk, 0, stream>>>(Wd4, wp4h, wp4l, 784, 1000, 896, 1024);

    // ---- encoder, np-exact f32 (BLAS-order FMA chains) ----
    for (int q = 0; q < NQn; ++q) {
        const float* Xq = X + (size_t)q * MQ * 784;
        np_gemm4<1, 4, 2><<<eg1, blk, 0, stream>>>(Xq, we1p, be1, h1, 1000, 1024, 800, 784, 784);
        np_gemm4<1, 4, 2><<<eg2, blk, 0, stream>>>(h1, we2p, be2, h2, 500, 512, 1024, 1024, 1024);
        np_gemm4<1, 2, 1><<<eg3, blk, 0, stream>>>(h2, we3p, be3, h3, 300, 320, 512, 512, 512);
        np_gemm4<0, 1, 1><<<eg4, blk, 0, stream>>>(h3, we4p, be4,
                                                   zenc + (size_t)q * MQ * 64, 64, 64, 320, 320, 320);
    }

    // ---- nearest-neighbor: np-exact, no refine ----
    k_norm2<<<dim3((KC + 255) / 256), blk, 0, stream>>>(emb, e2, KC);
    k_norm2<<<dim3((B + 255) / 256),  blk, 0, stream>>>(zenc, z2, B);

    k_nearest<<<dim3(64, 16), blk, 0, stream>>>(zenc, emb, z2, e2, 256, pd, pi);
    k_reduce <<<dim3(B / 256), blk, 0, stream>>>(pd, pi, 16, B, idx1);
    k_gather_split<<<dim3(B), dim3(64), 0, stream>>>(emb, idx1, zembh, zembl, KC);

    k_nearest<<<dim3(16, 64), blk, 0, stream>>>(emb, zenc, e2, z2, 256, pd, pi);
    k_reduce <<<dim3(KC / 256), blk, 0, stream>>>(pd, pi, 64, KC, idx2);
    k_gather <<<dim3(KC), dim3(64), 0, stream>>>(zenc, idx2, out + OFF3, B);

    // ---- decoder: pre-split planes + global_load_lds MFMA GEMM ----
    for (int q = 0; q < NQn; ++q) {
        gemm_planes<2, 1><<<dq1, blk, 0, stream>>>(
            zembh + (size_t)q * MQ * 64, zembl + (size_t)q * MQ * 64,
            wp1h, wp1l, bd1, nullptr, nullptr, d1h, d1l, 300, 64, 320);
        gemm_planes<2, 1><<<dq2, blk, 0, stream>>>(
            d1h, d1l, wp2h, wp2l, bd2, nullptr, nullptr, d2h, d2l, 500, 320, 512);
        gemm_planes<2, 1><<<dq3, blk, 0, stream>>>(
            d2h, d2l, wp3h, wp3l, bd3, nullptr, nullptr, d3h, d3l, 1000, 512, 1024);
        gemm_planes<3, 0><<<dq4, blk, 0, stream>>>(
            d3h, d3l, wp4h, wp4l, bd4,
            out + (size_t)q * MQ * 784, out + OFF2 + (size_t)q * MQ * 784,
            nullptr, nullptr, 784, 1024, 0);
    }

    (void)in_sizes; (void)n_in; (void)out_size;
}

// Round 8
// 1528.800 us; speedup vs baseline: 1.0570x; 1.0096x over previous
//
#include <hip/hip_runtime.h>
#include <hip/hip_bf16.h>
#include <math.h>

typedef __bf16 bf16_t;
typedef __bf16 bf16x8 __attribute__((ext_vector_type(8)));
typedef __bf16 bf16x4 __attribute__((ext_vector_type(4)));
typedef float f32x4 __attribute__((ext_vector_type(4)));

// async global->LDS, 16B per lane (linear LDS dest = wave base + lane*16)
__device__ __forceinline__ void gload16(const void* g, void* l)
{
    __builtin_amdgcn_global_load_lds(
        (const __attribute__((address_space(1))) void*)g,
        (__attribute__((address_space(3))) void*)l, 16, 0, 0);
}

// ---------------- np-exact f32 GEMM (encoder), v5 ----------------
// Round 17: r5 structure (k-major tiles, gload_lds staging, XOR-swizzled
// source, 8x8 per-thread tile = best measured 375us) + ZERO-VGPR LDS
// double-buffer (T3 minimum 2-phase): stage tile t+1 into buf^1 BEFORE
// computing tile t, ONE __syncthreads per tile. The barrier's vmcnt(0)
// drain is then cheap: the staged loads had the whole FMA phase (~4k cyc)
// to land. r5 exposed the full staging latency between two back-to-back
// barriers (~50% of its time per the corrected pipe-floor model:
// VALU 85us + LDS 128us vs measured 375us). r1 lesson: register-prefetch
// dbuf costs 120 VGPR and halves occupancy; gload_lds dbuf costs only LDS
// (64KB at CB=2 -> still 2 blocks/CU; 48KB at CB=1).
// Numerics bit-exact: staging order only; ascending-k __fmaf_rn chains.
template<int ACT, int CB>   // ACT: 0 none, 1 relu;  BM=128, BN=CB*64
__global__ __launch_bounds__(256)
void np_gemm5(const float* __restrict__ A, const float* __restrict__ W,
              const float* __restrict__ bias, float* __restrict__ C,
              int N, int Cstride, int KP, int KA, int Kreal)
{
    __shared__ __align__(16) float sA[2 * 128 * 32];
    __shared__ __align__(16) float sB[2 * CB * 64 * 32];
    const int tid = threadIdx.x;
    const int tx  = tid & 15, ty = tid >> 4;
    const int bRow = blockIdx.x * 128, bCol = blockIdx.y * (CB * 64);

    float acc[8][CB * 4];
#pragma unroll
    for (int i = 0; i < 8; ++i)
#pragma unroll
        for (int j = 0; j < CB * 4; ++j) acc[i][j] = 0.f;

    const int aswz = ty & 7;   // (arow>>2)&7 == ty&7 (arow = ib*64+ty*4+i)
    const int bswz = tx & 7;   // (brow>>2)&7 == tx&7 (brow = jb*64+tx*4+j)

    // stage one 32-k tile into buffer b (pure async copy; L1 K-edge tile
    // falls back to predicated reg staging with zero fill)
    auto stage = [&](int b, int k0) {
        float* dA = sA + b * (128 * 32);
        float* dB = sB + b * (CB * 64 * 32);
        if (k0 + 32 <= Kreal) {
#pragma unroll
            for (int i = 0; i < 4; ++i) {
                int L = tid + i * 256;
                int r = L >> 3, cc = L & 7;
                int gc = cc ^ ((r >> 2) & 7);
                gload16(A + (size_t)(bRow + r) * KA + (k0 + gc * 4), dA + L * 4);
            }
        } else {
#pragma unroll
            for (int i = 0; i < 4; ++i) {
                int L = tid + i * 256;
                int r = L >> 3, cc = L & 7;
                int gc = cc ^ ((r >> 2) & 7);
                int gk = k0 + gc * 4;
                float4 v = make_float4(0.f, 0.f, 0.f, 0.f);
                if (gk < Kreal) v = *(const float4*)(A + (size_t)(bRow + r) * KA + gk);
                *(float4*)(dA + L * 4) = v;
            }
        }
#pragma unroll
        for (int i = 0; i < CB * 2; ++i) {
            int L = tid + i * 256;
            int r = L >> 3, cc = L & 7;
            int gc = cc ^ ((r >> 2) & 7);
            gload16(W + (size_t)(bCol + r) * KP + (k0 + gc * 4), dB + L * 4);
        }
    };

    const int nt = KP >> 5;
    stage(0, 0);
    __syncthreads();          // buf0 ready (vmcnt+lgkm drained)

    int buf = 0;
    for (int t = 0; t < nt; ++t) {
        if (t + 1 < nt) stage(buf ^ 1, (t + 1) << 5);   // issue early: hides under FMAs

        const float* pA = sA + buf * (128 * 32);
        const float* pB = sB + buf * (CB * 64 * 32);
#pragma unroll
        for (int kc = 0; kc < 8; ++kc) {       // strictly ascending k
            const int ac = ((kc ^ aswz) << 2);
            const int bc = ((kc ^ bswz) << 2);
            float4 b4[CB][4];
#pragma unroll
            for (int jb = 0; jb < CB; ++jb)
#pragma unroll
                for (int j = 0; j < 4; ++j)
                    b4[jb][j] = *(const float4*)(pB + (jb * 64 + tx * 4 + j) * 32 + bc);
#pragma unroll
            for (int ib = 0; ib < 2; ++ib)
#pragma unroll
                for (int i = 0; i < 4; ++i) {
                    float4 a4 = *(const float4*)(pA + (ib * 64 + ty * 4 + i) * 32 + ac);
#pragma unroll
                    for (int jb = 0; jb < CB; ++jb)
#pragma unroll
                        for (int j = 0; j < 4; ++j) {
                            float& o = acc[ib * 4 + i][jb * 4 + j];
                            o = __fmaf_rn(a4.x, b4[jb][j].x, o);
                            o = __fmaf_rn(a4.y, b4[jb][j].y, o);
                            o = __fmaf_rn(a4.z, b4[jb][j].z, o);
                            o = __fmaf_rn(a4.w, b4[jb][j].w, o);
                        }
                }
        }
        __syncthreads();      // drains next-tile stage + guards buf reuse
        buf ^= 1;
    }

#pragma unroll
    for (int jb = 0; jb < CB; ++jb) {
        int col4 = bCol + jb * 64 + tx * 4;
        if (col4 >= Cstride) continue;     // Cstride%4==0 -> whole float4 ok
#pragma unroll
        for (int ib = 0; ib < 2; ++ib)
#pragma unroll
            for (int i = 0; i < 4; ++i) {
                int row = bRow + ib * 64 + ty * 4 + i;
                float ov[4];
#pragma unroll
                for (int j = 0; j < 4; ++j) {
                    int col = col4 + j;
                    float v = 0.f;
                    if (col < N) {
                        v = __fadd_rn(acc[ib * 4 + i][jb * 4 + j], bias[col]);
                        if (ACT == 1) v = v > 0.f ? v : 0.f;
                    }
                    ov[j] = v;
                }
                *(float4*)(C + (size_t)row * Cstride + col4) =
                    make_float4(ov[0], ov[1], ov[2], ov[3]);
            }
    }
}

// pad f32 matrix [rows][K] -> [rowsP][Kp] with zeros (encoder weights)
__global__ void k_padw(const float* __restrict__ src, float* __restrict__ dst,
                       int rows, int K, int rowsP, int Kp)
{
    int e = blockIdx.x * 256 + threadIdx.x;
    if (e >= rowsP * Kp) return;
    int r = e / Kp, k = e - r * Kp;
    dst[e] = (r < rows && k < K) ? src[(size_t)r * K + k] : 0.f;
}

// ---------------- split helper: f32 -> (bf16 hi, bf16 lo) planes ----------
__global__ void k_split(const float* __restrict__ src, bf16_t* __restrict__ hi,
                        bf16_t* __restrict__ lo, int rows, int K, int rowsP, int Kp)
{
    int e = blockIdx.x * 256 + threadIdx.x;
    if (e >= rowsP * Kp) return;
    int r = e / Kp, k = e - r * Kp;
    float v = (r < rows && k < K) ? src[(size_t)r * K + k] : 0.f;
    bf16_t h = (bf16_t)v;
    bf16_t l = (bf16_t)(v - (float)h);
    hi[e] = h; lo[e] = l;
}

// ---------------- bf16 MFMA GEMM on pre-split planes (decoder), dbuf ------
// Round 17: same zero-VGPR gload_lds double-buffer, one barrier per tile.
template<int ACT, int OUT>
__global__ __launch_bounds__(256)
void gemm_planes(const bf16_t* __restrict__ Ahi, const bf16_t* __restrict__ Alo,
                 const bf16_t* __restrict__ Bhi, const bf16_t* __restrict__ Blo,
                 const float* __restrict__ bias,
                 float* __restrict__ C0, float* __restrict__ C1,
                 bf16_t* __restrict__ Phi, bf16_t* __restrict__ Plo,
                 int N, int Kp, int Kpn)
{
    __shared__ __align__(16) bf16_t sA[2][2][128][32];   // [buf][term][row][k]
    __shared__ __align__(16) bf16_t sB[2][2][128][32];

    const int tid  = threadIdx.x;
    const int bRow = blockIdx.x * 128;
    const int bCol = blockIdx.y * 128;
    const int wave = tid >> 6;
    const int lane = tid & 63;
    const int wr   = (wave >> 1) * 64;
    const int wc   = (wave & 1) * 64;
    const int quad = lane >> 4;
    const int l15  = lane & 15;

    f32x4 acc[4][4];
#pragma unroll
    for (int i = 0; i < 4; ++i)
#pragma unroll
        for (int j = 0; j < 4; ++j) acc[i][j] = (f32x4){0.f, 0.f, 0.f, 0.f};

    auto stage = [&](int b, int k0) {
#pragma unroll
        for (int i = 0; i < 2; ++i) {
            int c    = tid + i * 256;
            int row  = c >> 2;
            int koff = (c & 3) << 3;
            size_t ga = (size_t)(bRow + row) * Kp + (k0 + koff);
            size_t gb = (size_t)(bCol + row) * Kp + (k0 + koff);
            gload16(Ahi + ga, &sA[b][0][row][koff]);
            gload16(Alo + ga, &sA[b][1][row][koff]);
            gload16(Bhi + gb, &sB[b][0][row][koff]);
            gload16(Blo + gb, &sB[b][1][row][koff]);
        }
    };

    const int nt = Kp >> 5;
    stage(0, 0);
    __syncthreads();

    int buf = 0;
    for (int t = 0; t < nt; ++t) {
        if (t + 1 < nt) stage(buf ^ 1, (t + 1) << 5);

        bf16x8 af[2][4], bfr[2][4];
#pragma unroll
        for (int tt = 0; tt < 2; ++tt)
#pragma unroll
            for (int i = 0; i < 4; ++i) {
                af[tt][i]  = *(const bf16x8*)&sA[buf][tt][wr + i * 16 + l15][quad * 8];
                bfr[tt][i] = *(const bf16x8*)&sB[buf][tt][wc + i * 16 + l15][quad * 8];
            }
#pragma unroll
        for (int i = 0; i < 4; ++i)
#pragma unroll
            for (int j = 0; j < 4; ++j)
#pragma unroll
                for (int ta = 0; ta < 2; ++ta)
#pragma unroll
                    for (int tb = 0; tb < 2 - ta; ++tb)
                        acc[i][j] = __builtin_amdgcn_mfma_f32_16x16x32_bf16(
                            af[ta][i], bfr[tb][j], acc[i][j], 0, 0, 0);

        __syncthreads();
        buf ^= 1;
    }

#pragma unroll
    for (int j = 0; j < 4; ++j) {
        int col = bCol + wc + j * 16 + l15;
        if (OUT == 0) {
            if (col >= N) continue;
            float bv = bias[col];
#pragma unroll
            for (int i = 0; i < 4; ++i)
#pragma unroll
                for (int r = 0; r < 4; ++r) {
                    int row = bRow + wr + i * 16 + quad * 4 + r;
                    float v = acc[i][j][r] + bv;
                    if (ACT == 1)      v = v > 0.f ? v : 0.f;
                    else if (ACT == 2) v = v >= 0.f ? v : 0.1f * v;
                    else if (ACT == 3) v = tanhf(v);
                    size_t o = (size_t)row * N + col;
                    C0[o] = v;
                    if (C1) C1[o] = v;
                }
        } else {
            if (col >= Kpn) continue;
            const bool real = col < N;
            float bv = real ? bias[col] : 0.f;
#pragma unroll
            for (int i = 0; i < 4; ++i)
#pragma unroll
                for (int r = 0; r < 4; ++r) {
                    int row = bRow + wr + i * 16 + quad * 4 + r;
                    float v = 0.f;
                    if (real) {
                        v = acc[i][j][r] + bv;
                        if (ACT == 1)      v = v > 0.f ? v : 0.f;
                        else if (ACT == 2) v = v >= 0.f ? v : 0.1f * v;
                        else if (ACT == 3) v = tanhf(v);
                    }
                    bf16_t h = (bf16_t)v;
                    bf16_t l = (bf16_t)(v - (float)h);
                    size_t o = (size_t)row * Kpn + col;
                    Phi[o] = h; Plo[o] = l;
                }
        }
    }
}

// np-exact nearest scan (bit-identical to np reference).
__global__ __launch_bounds__(256)
void k_nearest(const float* __restrict__ Q, const float* __restrict__ C,
               const float* __restrict__ q2a, const float* __restrict__ cn2,
               int chunk, float* __restrict__ pd, int* __restrict__ pi)
{
    __shared__ __align__(16) float sc[64][64];
    __shared__ __align__(16) float sn[64];
    const int tid = threadIdx.x;
    const int q   = blockIdx.x * 256 + tid;
    const int G   = gridDim.y;

    float qr[64];
    const float4* qp = (const float4*)(Q + (size_t)q * 64);
#pragma unroll
    for (int i = 0; i < 16; ++i) ((float4*)qr)[i] = qp[i];
    const float q2 = q2a[q];

    float best = 3.4e38f;
    int   bi   = 0x7fffffff;
    const int c0 = blockIdx.y * chunk;

    for (int cb = 0; cb < chunk; cb += 64) {
        __syncthreads();
        const float4* gp = (const float4*)(C + (size_t)(c0 + cb) * 64);
#pragma unroll
        for (int i = 0; i < 4; ++i) {
            int e = tid + i * 256;
            ((float4*)&sc[0][0])[e] = gp[e];
        }
        if (tid < 64) sn[tid] = cn2[c0 + cb + tid];
        __syncthreads();

        for (int c = 0; c < 64; c += 4) {
            float a0 = 0.f, a1 = 0.f, a2 = 0.f, a3 = 0.f;
            const float4* e0 = (const float4*)&sc[c + 0][0];
            const float4* e1 = (const float4*)&sc[c + 1][0];
            const float4* e2p = (const float4*)&sc[c + 2][0];
            const float4* e3 = (const float4*)&sc[c + 3][0];
#pragma unroll
            for (int z = 0; z < 16; ++z) {          // k ascending, chain order exact
                float4 q4 = ((float4*)qr)[z];
                float4 v0 = e0[z], v1 = e1[z], v2 = e2p[z], v3 = e3[z];
                a0 = __fmaf_rn(q4.x, v0.x, a0); a0 = __fmaf_rn(q4.y, v0.y, a0);
                a0 = __fmaf_rn(q4.z, v0.z, a0); a0 = __fmaf_rn(q4.w, v0.w, a0);
                a1 = __fmaf_rn(q4.x, v1.x, a1); a1 = __fmaf_rn(q4.y, v1.y, a1);
                a1 = __fmaf_rn(q4.z, v1.z, a1); a1 = __fmaf_rn(q4.w, v1.w, a1);
                a2 = __fmaf_rn(q4.x, v2.x, a2); a2 = __fmaf_rn(q4.y, v2.y, a2);
                a2 = __fmaf_rn(q4.z, v2.z, a2); a2 = __fmaf_rn(q4.w, v2.w, a2);
                a3 = __fmaf_rn(q4.x, v3.x, a3); a3 = __fmaf_rn(q4.y, v3.y, a3);
                a3 = __fmaf_rn(q4.z, v3.z, a3); a3 = __fmaf_rn(q4.w, v3.w, a3);
            }
            float d;
            d = __fadd_rn(__fsub_rn(q2, __fmul_rn(2.f, a0)), sn[c + 0]);
            if (d < best) { best = d; bi = c0 + cb + c + 0; }
            d = __fadd_rn(__fsub_rn(q2, __fmul_rn(2.f, a1)), sn[c + 1]);
            if (d < best) { best = d; bi = c0 + cb + c + 1; }
            d = __fadd_rn(__fsub_rn(q2, __fmul_rn(2.f, a2)), sn[c + 2]);
            if (d < best) { best = d; bi = c0 + cb + c + 2; }
            d = __fadd_rn(__fsub_rn(q2, __fmul_rn(2.f, a3)), sn[c + 3]);
            if (d < best) { best = d; bi = c0 + cb + c + 3; }
        }
    }
    pd[(size_t)q * G + blockIdx.y] = best;
    pi[(size_t)q * G + blockIdx.y] = bi;
}

__global__ void k_reduce(const float* __restrict__ pd, const int* __restrict__ pi,
                         int G, int NQ, int* __restrict__ out)
{
    int q = blockIdx.x * blockDim.x + threadIdx.x;
    if (q >= NQ) return;
    float best = 3.4e38f; int bi = 0;
    for (int g = 0; g < G; ++g) {
        float d = pd[(size_t)q * G + g];
        if (d < best) { best = d; bi = pi[(size_t)q * G + g]; }
    }
    out[q] = bi;
}

__global__ void k_gather(const float* __restrict__ src, const int* __restrict__ idx,
                         float* __restrict__ dst, int nsrc)
{
    int r = blockIdx.x, z = threadIdx.x;
    int i = idx[r];
    i = i < 0 ? 0 : (i >= nsrc ? nsrc - 1 : i);
    dst[(size_t)r * 64 + z] = src[(size_t)i * 64 + z];
}

// gather emb rows -> split bf16 planes (decoder layer-1 A input).
__global__ void k_gather_split(const float* __restrict__ src, const int* __restrict__ idx,
                               bf16_t* __restrict__ hi, bf16_t* __restrict__ lo, int nsrc)
{
    int r = blockIdx.x, z = threadIdx.x;
    int i = idx[r];
    i = i < 0 ? 0 : (i >= nsrc ? nsrc - 1 : i);
    float v = src[(size_t)i * 64 + z];
    bf16_t h = (bf16_t)v;
    bf16_t l = (bf16_t)(v - (float)h);
    hi[(size_t)r * 64 + z] = h;
    lo[(size_t)r * 64 + z] = l;
}

// numpy pairwise row norm^2 (n=64), bit-exact.
__global__ void k_norm2(const float* __restrict__ s, float* __restrict__ o, int rows)
{
    int r0 = blockIdx.x * blockDim.x + threadIdx.x;
    if (r0 >= rows) return;
    const float* p = s + (size_t)r0 * 64;
    float r[8];
#pragma unroll
    for (int j = 0; j < 8; ++j) r[j] = __fmul_rn(p[j], p[j]);
#pragma unroll
    for (int i = 8; i < 64; i += 8)
#pragma unroll
        for (int j = 0; j < 8; ++j)
            r[j] = __fadd_rn(r[j], __fmul_rn(p[i + j], p[i + j]));
    float t01 = __fadd_rn(r[0], r[1]), t23 = __fadd_rn(r[2], r[3]);
    float t45 = __fadd_rn(r[4], r[5]), t67 = __fadd_rn(r[6], r[7]);
    o[r0] = __fadd_rn(__fadd_rn(t01, t23), __fadd_rn(t45, t67));
}

extern "C" void kernel_launch(void* const* d_in, const int* in_sizes, int n_in,
                              void* d_out, int out_size, void* d_ws, size_t ws_size,
                              hipStream_t stream)
{
    const int B  = 16384;
    const int KC = 4096;

    const float* X   = (const float*)d_in[0];
    const float* We1 = (const float*)d_in[1];
    const float* be1 = (const float*)d_in[2];
    const float* We2 = (const float*)d_in[3];
    const float* be2 = (const float*)d_in[4];
    const float* We3 = (const float*)d_in[5];
    const float* be3 = (const float*)d_in[6];
    const float* We4 = (const float*)d_in[7];
    const float* be4 = (const float*)d_in[8];
    const float* emb = (const float*)d_in[9];
    const float* Wd1 = (const float*)d_in[10];
    const float* bd1 = (const float*)d_in[11];
    const float* Wd2 = (const float*)d_in[12];
    const float* bd2 = (const float*)d_in[13];
    const float* Wd3 = (const float*)d_in[14];
    const float* bd3 = (const float*)d_in[15];
    const float* Wd4 = (const float*)d_in[16];
    const float* bd4 = (const float*)d_in[17];

    float* out = (float*)d_out;
    const size_t OFF1 = (size_t)B * 784;
    const size_t OFF2 = OFF1 + (size_t)B * 64;
    const size_t OFF3 = OFF2 + (size_t)B * 784;
    float* zenc = out + OFF1;

    // dynamic batch tiling (ws_size constant across calls -> graph-safe).
    const size_t FIXED = (size_t)24 << 20;
    int MQ;
    if      (ws_size >= FIXED + (size_t)16384 * 7424) MQ = 16384;
    else if (ws_size >= FIXED + (size_t)8192  * 7424) MQ = 8192;
    else                                              MQ = 4096;
    const int NQn = B / MQ;

    char* ws = (char*)d_ws;
    size_t off = 0;
    auto alloc = [&](size_t bytes) -> void* {
        void* p = ws + off;
        off = (off + bytes + 255) & ~(size_t)255;
        return p;
    };
    float* pd    = (float*)alloc((size_t)262144 * 4);
    int*   pi    = (int*)alloc((size_t)262144 * 4);
    int*   idx1  = (int*)alloc((size_t)B * 4);
    int*   idx2  = (int*)alloc((size_t)KC * 4);
    float* e2    = (float*)alloc((size_t)KC * 4);
    float* z2    = (float*)alloc((size_t)B * 4);
    // encoder padded weights (f32, [NP][KP] zeros)
    float* we1p = (float*)alloc((size_t)1024 * 800 * 4);
    float* we2p = (float*)alloc((size_t)512 * 1024 * 4);
    float* we3p = (float*)alloc((size_t)384 * 512 * 4);
    float* we4p = (float*)alloc((size_t)128 * 320 * 4);
    // decoder split bf16 planes: zemb (full B) + weights
    bf16_t* zembh = (bf16_t*)alloc((size_t)B * 64 * 2);
    bf16_t* zembl = (bf16_t*)alloc((size_t)B * 64 * 2);
    bf16_t* wp1h = (bf16_t*)alloc((size_t)384 * 64 * 2);
    bf16_t* wp1l = (bf16_t*)alloc((size_t)384 * 64 * 2);
    bf16_t* wp2h = (bf16_t*)alloc((size_t)512 * 320 * 2);
    bf16_t* wp2l = (bf16_t*)alloc((size_t)512 * 320 * 2);
    bf16_t* wp3h = (bf16_t*)alloc((size_t)1024 * 512 * 2);
    bf16_t* wp3l = (bf16_t*)alloc((size_t)1024 * 512 * 2);
    bf16_t* wp4h = (bf16_t*)alloc((size_t)896 * 1024 * 2);
    bf16_t* wp4l = (bf16_t*)alloc((size_t)896 * 1024 * 2);
    // big shared region: encoder padded f32 h1..h3, then decoder act planes
    char* big = (char*)alloc((size_t)MQ * 7424);
    float* h1 = (float*)big;                           // MQ x 1024 f32 (N=1000)
    float* h2 = (float*)(big + (size_t)MQ * 4096);     // MQ x 512  (N=500)
    float* h3 = (float*)(big + (size_t)MQ * 6144);     // MQ x 320  (N=300)
    bf16_t* d1h = (bf16_t*)big;                        // MQ x 320 bf16
    bf16_t* d1l = (bf16_t*)(big + (size_t)MQ * 640);
    bf16_t* d2h = (bf16_t*)(big + (size_t)MQ * 1280);  // MQ x 512
    bf16_t* d2l = (bf16_t*)(big + (size_t)MQ * 2304);
    bf16_t* d3h = (bf16_t*)(big + (size_t)MQ * 3328);  // MQ x 1024
    bf16_t* d3l = (bf16_t*)(big + (size_t)MQ * 5376);

    dim3 blk(256);
    // encoder grids: x = row-panels (XCD locality), y = col-blocks (r5 shapes)
    const dim3 eg1(MQ / 128, 8), eg2(MQ / 128, 8), eg3(MQ / 128, 5), eg4(MQ / 128, 1);
    // decoder grids: same axis order
    const dim3 dq1(MQ / 128, 3), dq2(MQ / 128, 4), dq3(MQ / 128, 8), dq4(MQ / 128, 7);

    // ---- weight pre-pad / pre-split (tiny, input-only dependency) ----
    k_padw<<<dim3((1024 * 800 + 255) / 256), blk, 0, stream>>>(We1, we1p, 1000, 784, 1024, 800);
    k_padw<<<dim3((512 * 1024 + 255) / 256), blk, 0, stream>>>(We2, we2p, 500, 1000, 512, 1024);
    k_padw<<<dim3((384 * 512  + 255) / 256), blk, 0, stream>>>(We3, we3p, 300, 500, 384, 512);
    k_padw<<<dim3((128 * 320  + 255) / 256), blk, 0, stream>>>(We4, we4p, 64, 300, 128, 320);
    k_split<<<dim3((384 * 64   + 255) / 256), blk, 0, stream>>>(Wd1, wp1h, wp1l, 300, 64, 384, 64);
    k_split<<<dim3((512 * 320  + 255) / 256), blk, 0, stream>>>(Wd2, wp2h, wp2l, 500, 300, 512, 320);
    k_split<<<dim3((1024 * 512 + 255) / 256), blk, 0, stream>>>(Wd3, wp3h, wp3l, 1000, 500, 1024, 512);
    k_split<<<dim3((896 * 1024 + 255) / 256), blk, 0, stream>>>(Wd4, wp4h, wp4l, 784, 1000, 896, 1024);

    // ---- encoder, np-exact f32 (BLAS-order FMA chains) ----
    for (int q = 0; q < NQn; ++q) {
        const float* Xq = X + (size_t)q * MQ * 784;
        np_gemm5<1, 2><<<eg1, blk, 0, stream>>>(Xq, we1p, be1, h1, 1000, 1024, 800, 784, 784);
        np_gemm5<1, 1><<<eg2, blk, 0, stream>>>(h1, we2p, be2, h2, 500, 512, 1024, 1024, 1024);
        np_gemm5<1, 1><<<eg3, blk, 0, stream>>>(h2, we3p, be3, h3, 300, 320, 512, 512, 512);
        np_gemm5<0, 1><<<eg4, blk, 0, stream>>>(h3, we4p, be4,
                                                zenc + (size_t)q * MQ * 64, 64, 64, 320, 320, 320);
    }

    // ---- nearest-neighbor: np-exact, no refine ----
    k_norm2<<<dim3((KC + 255) / 256), blk, 0, stream>>>(emb, e2, KC);
    k_norm2<<<dim3((B + 255) / 256),  blk, 0, stream>>>(zenc, z2, B);

    k_nearest<<<dim3(64, 16), blk, 0, stream>>>(zenc, emb, z2, e2, 256, pd, pi);
    k_reduce <<<dim3(B / 256), blk, 0, stream>>>(pd, pi, 16, B, idx1);
    k_gather_split<<<dim3(B), dim3(64), 0, stream>>>(emb, idx1, zembh, zembl, KC);

    k_nearest<<<dim3(16, 64), blk, 0, stream>>>(emb, zenc, e2, z2, 256, pd, pi);
    k_reduce <<<dim3(KC / 256), blk, 0, stream>>>(pd, pi, 64, KC, idx2);
    k_gather <<<dim3(KC), dim3(64), 0, stream>>>(zenc, idx2, out + OFF3, B);

    // ---- decoder: pre-split planes + dbuf global_load_lds MFMA GEMM ----
    for (int q = 0; q < NQn; ++q) {
        gemm_planes<2, 1><<<dq1, blk, 0, stream>>>(
            zembh + (size_t)q * MQ * 64, zembl + (size_t)q * MQ * 64,
            wp1h, wp1l, bd1, nullptr, nullptr, d1h, d1l, 300, 64, 320);
        gemm_planes<2, 1><<<dq2, blk, 0, stream>>>(
            d1h, d1l, wp2h, wp2l, bd2, nullptr, nullptr, d2h, d2l, 500, 320, 512);
        gemm_planes<2, 1><<<dq3, blk, 0, stream>>>(
            d2h, d2l, wp3h, wp3l, bd3, nullptr, nullptr, d3h, d3l, 1000, 512, 1024);
        gemm_planes<3, 0><<<dq4, blk, 0, stream>>>(
            d3h, d3l, wp4h, wp4l, bd4,
            out + (size_t)q * MQ * 784, out + OFF2 + (size_t)q * MQ * 784,
            nullptr, nullptr, 784, 1024, 0);
    }

    (void)in_sizes; (void)n_in; (void)out_size;
}

// Round 9
// 1381.190 us; speedup vs baseline: 1.1700x; 1.1069x over previous
//
#include <hip/hip_runtime.h>
#include <hip/hip_bf16.h>
#include <math.h>

typedef __bf16 bf16_t;
typedef __bf16 bf16x8 __attribute__((ext_vector_type(8)));
typedef __bf16 bf16x4 __attribute__((ext_vector_type(4)));
typedef float f32x4 __attribute__((ext_vector_type(4)));

// async global->LDS, 16B per lane (linear LDS dest = wave base + lane*16)
__device__ __forceinline__ void gload16(const void* g, void* l)
{
    __builtin_amdgcn_global_load_lds(
        (const __attribute__((address_space(1))) void*)g,
        (__attribute__((address_space(3))) void*)l, 16, 0, 0);
}

// ---------------- np-exact f32 GEMM (encoder), r5 champion ----------------
// Structure locked by rounds 5-8 measurements:
//  - k-major LDS tiles [row][32], BK=32: 128B rows -> b128 reads hit all 8
//    bank-groups; A-reads broadcast (free), B-reads 2-way (free). BK=16
//    would re-create 4-way conflicts; don't.
//  - gload_lds width-16 staging, XOR-swizzled global source (T2 via m173).
//  - 8x8 per-thread tile = optimal LDS-reads/FMA under BM+BN<=256.
//  - 32KB LDS/block, plain __launch_bounds__(256): 2 blocks/CU. Empirical
//    LDS pool for occupancy = 64KB/CU (r7: 48KB->1 blk; r8: 64KB->1 blk);
//    any structure >32KB/block loses ~135us. No dbuf, no reg-prefetch
//    (r1: +120 VGPR; r8: +32KB — both halve occupancy and regress).
//  - grid x = row-panels so all col-blocks of a panel land on one XCD
//    (r4->r5: FETCH 211->96MB).
// Measured wall: LDS-BW 256us (L1) vs VALU 170us -> VALUBusy ~68%. The
// ~120us residual is barrier-exposed staging; 4 pipelining attempts all
// cost more than they recovered. This is the structure's roofline.
// Numerics: per-C-element single-accumulator ascending-k __fmaf_rn chain
// (np/BLAS-exact); pad-k FMAs are fma(0,0,acc) no-ops.
template<int ACT, int CB>   // ACT: 0 none, 1 relu;  BM=128, BN=CB*64
__global__ __launch_bounds__(256)
void np_gemm(const float* __restrict__ A, const float* __restrict__ W,
             const float* __restrict__ bias, float* __restrict__ C,
             int N, int Cstride, int KP, int KA, int Kreal)
{
    __shared__ __align__(16) float sA[128 * 32];
    __shared__ __align__(16) float sB[CB * 64 * 32];
    const int tid = threadIdx.x;
    const int tx  = tid & 15, ty = tid >> 4;
    const int bRow = blockIdx.x * 128, bCol = blockIdx.y * (CB * 64);

    float acc[8][CB * 4];
#pragma unroll
    for (int i = 0; i < 8; ++i)
#pragma unroll
        for (int j = 0; j < CB * 4; ++j) acc[i][j] = 0.f;

    const int aswz = ty & 7;   // (arow>>2)&7 == ty&7 (arow = ib*64+ty*4+i)
    const int bswz = tx & 7;   // (brow>>2)&7 == tx&7 (brow = jb*64+tx*4+j)

    for (int k0 = 0; k0 < KP; k0 += 32) {
        __syncthreads();
        if (k0 + 32 <= Kreal) {
            // full tile: pure async copy, source pre-swizzled
#pragma unroll
            for (int i = 0; i < 4; ++i) {
                int L = tid + i * 256;
                int r = L >> 3, cc = L & 7;
                int gc = cc ^ ((r >> 2) & 7);
                gload16(A + (size_t)(bRow + r) * KA + (k0 + gc * 4), sA + L * 4);
            }
        } else {
            // layer-1 K edge (k0=768, Kreal=784): predicated reg staging, zero pad
#pragma unroll
            for (int i = 0; i < 4; ++i) {
                int L = tid + i * 256;
                int r = L >> 3, cc = L & 7;
                int gc = cc ^ ((r >> 2) & 7);
                int gk = k0 + gc * 4;
                float4 v = make_float4(0.f, 0.f, 0.f, 0.f);
                if (gk < Kreal) v = *(const float4*)(A + (size_t)(bRow + r) * KA + gk);
                *(float4*)(sA + L * 4) = v;
            }
        }
#pragma unroll
        for (int i = 0; i < CB * 2; ++i) {
            int L = tid + i * 256;
            int r = L >> 3, cc = L & 7;
            int gc = cc ^ ((r >> 2) & 7);
            gload16(W + (size_t)(bCol + r) * KP + (k0 + gc * 4), sB + L * 4);
        }
        __syncthreads();

#pragma unroll
        for (int kc = 0; kc < 8; ++kc) {       // strictly ascending k
            const int ac = ((kc ^ aswz) << 2);
            const int bc = ((kc ^ bswz) << 2);
            float4 b4[CB][4];
#pragma unroll
            for (int jb = 0; jb < CB; ++jb)
#pragma unroll
                for (int j = 0; j < 4; ++j)
                    b4[jb][j] = *(const float4*)(sB + (jb * 64 + tx * 4 + j) * 32 + bc);
#pragma unroll
            for (int ib = 0; ib < 2; ++ib)
#pragma unroll
                for (int i = 0; i < 4; ++i) {
                    float4 a4 = *(const float4*)(sA + (ib * 64 + ty * 4 + i) * 32 + ac);
#pragma unroll
                    for (int jb = 0; jb < CB; ++jb)
#pragma unroll
                        for (int j = 0; j < 4; ++j) {
                            float& o = acc[ib * 4 + i][jb * 4 + j];
                            o = __fmaf_rn(a4.x, b4[jb][j].x, o);
                            o = __fmaf_rn(a4.y, b4[jb][j].y, o);
                            o = __fmaf_rn(a4.z, b4[jb][j].z, o);
                            o = __fmaf_rn(a4.w, b4[jb][j].w, o);
                        }
                }
        }
    }

#pragma unroll
    for (int jb = 0; jb < CB; ++jb) {
        int col4 = bCol + jb * 64 + tx * 4;
        if (col4 >= Cstride) continue;     // Cstride%4==0 -> whole float4 ok
#pragma unroll
        for (int ib = 0; ib < 2; ++ib)
#pragma unroll
            for (int i = 0; i < 4; ++i) {
                int row = bRow + ib * 64 + ty * 4 + i;
                float ov[4];
#pragma unroll
                for (int j = 0; j < 4; ++j) {
                    int col = col4 + j;
                    float v = 0.f;
                    if (col < N) {
                        v = __fadd_rn(acc[ib * 4 + i][jb * 4 + j], bias[col]);
                        if (ACT == 1) v = v > 0.f ? v : 0.f;
                    }
                    ov[j] = v;
                }
                *(float4*)(C + (size_t)row * Cstride + col4) =
                    make_float4(ov[0], ov[1], ov[2], ov[3]);
            }
    }
}

// ---- fused weight prep: all 4 encoder pads in ONE kernel (launch trim) ----
struct PadSeg { const float* src; float* dst; int rows, K, rowsP, Kp, base; };

__global__ void k_padw4(const float* s0, float* d0, const float* s1, float* d1,
                        const float* s2, float* d2, const float* s3, float* d3)
{
    // segment element counts (compile-time constants for this problem)
    // 0: 1024x800  1: 512x1024  2: 384x512  3: 128x320
    int e = blockIdx.x * 256 + threadIdx.x;
    const float* src; float* dst; int rows, K, rowsP, Kp;
    if (e < 819200)        { src=s0; dst=d0; rows=1000; K=784;  rowsP=1024; Kp=800;  }
    else if (e < 1343488)  { e -= 819200;  src=s1; dst=d1; rows=500;  K=1000; rowsP=512;  Kp=1024; }
    else if (e < 1540096)  { e -= 1343488; src=s2; dst=d2; rows=300;  K=500;  rowsP=384;  Kp=512;  }
    else if (e < 1581056)  { e -= 1540096; src=s3; dst=d3; rows=64;   K=300;  rowsP=128;  Kp=320;  }
    else return;
    int r = e / Kp, k = e - r * Kp;
    dst[e + 0] = (r < rows && k < K) ? src[(size_t)r * K + k] : 0.f;
}

// ---- fused weight split: all 4 decoder splits in ONE kernel ----
__global__ void k_split4(const float* s0, bf16_t* h0, bf16_t* l0,
                         const float* s1, bf16_t* h1, bf16_t* l1,
                         const float* s2, bf16_t* h2, bf16_t* l2,
                         const float* s3, bf16_t* h3, bf16_t* l3)
{
    // 0: 384x64  1: 512x320  2: 1024x512  3: 896x1024
    int e = blockIdx.x * 256 + threadIdx.x;
    const float* src; bf16_t* hi; bf16_t* lo; int rows, K, Kp;
    if (e < 24576)         { src=s0; hi=h0; lo=l0; rows=300;  K=64;   Kp=64;   }
    else if (e < 188416)   { e -= 24576;  src=s1; hi=h1; lo=l1; rows=500;  K=300;  Kp=320;  }
    else if (e < 712704)   { e -= 188416; src=s2; hi=h2; lo=l2; rows=1000; K=500;  Kp=512;  }
    else if (e < 1630208)  { e -= 712704; src=s3; hi=h3; lo=l3; rows=784;  K=1000; Kp=1024; }
    else return;
    int r = e / Kp, k = e - r * Kp;
    float v = (r < rows && k < K) ? src[(size_t)r * K + k] : 0.f;
    bf16_t h = (bf16_t)v;
    bf16_t l = (bf16_t)(v - (float)h);
    hi[e] = h; lo[e] = l;
}

// ---------------- bf16 MFMA GEMM on pre-split planes (decoder) ------------
template<int ACT, int OUT>
__global__ __launch_bounds__(256)
void gemm_planes(const bf16_t* __restrict__ Ahi, const bf16_t* __restrict__ Alo,
                 const bf16_t* __restrict__ Bhi, const bf16_t* __restrict__ Blo,
                 const float* __restrict__ bias,
                 float* __restrict__ C0, float* __restrict__ C1,
                 bf16_t* __restrict__ Phi, bf16_t* __restrict__ Plo,
                 int N, int Kp, int Kpn)
{
    __shared__ __align__(16) bf16_t sA[2][128][32];
    __shared__ __align__(16) bf16_t sB[2][128][32];

    const int tid  = threadIdx.x;
    const int bRow = blockIdx.x * 128;
    const int bCol = blockIdx.y * 128;
    const int wave = tid >> 6;
    const int lane = tid & 63;
    const int wr   = (wave >> 1) * 64;
    const int wc   = (wave & 1) * 64;
    const int quad = lane >> 4;
    const int l15  = lane & 15;

    f32x4 acc[4][4];
#pragma unroll
    for (int i = 0; i < 4; ++i)
#pragma unroll
        for (int j = 0; j < 4; ++j) acc[i][j] = (f32x4){0.f, 0.f, 0.f, 0.f};

    for (int k0 = 0; k0 < Kp; k0 += 32) {
        __syncthreads();
#pragma unroll
        for (int i = 0; i < 2; ++i) {
            int c    = tid + i * 256;
            int row  = c >> 2;
            int koff = (c & 3) << 3;
            size_t ga = (size_t)(bRow + row) * Kp + (k0 + koff);
            size_t gb = (size_t)(bCol + row) * Kp + (k0 + koff);
            gload16(Ahi + ga, &sA[0][row][koff]);
            gload16(Alo + ga, &sA[1][row][koff]);
            gload16(Bhi + gb, &sB[0][row][koff]);
            gload16(Blo + gb, &sB[1][row][koff]);
        }
        __syncthreads();

        bf16x8 af[2][4], bfr[2][4];
#pragma unroll
        for (int t = 0; t < 2; ++t)
#pragma unroll
            for (int i = 0; i < 4; ++i) {
                af[t][i]  = *(const bf16x8*)&sA[t][wr + i * 16 + l15][quad * 8];
                bfr[t][i] = *(const bf16x8*)&sB[t][wc + i * 16 + l15][quad * 8];
            }
#pragma unroll
        for (int i = 0; i < 4; ++i)
#pragma unroll
            for (int j = 0; j < 4; ++j)
#pragma unroll
                for (int ta = 0; ta < 2; ++ta)
#pragma unroll
                    for (int tb = 0; tb < 2 - ta; ++tb)
                        acc[i][j] = __builtin_amdgcn_mfma_f32_16x16x32_bf16(
                            af[ta][i], bfr[tb][j], acc[i][j], 0, 0, 0);
    }

#pragma unroll
    for (int j = 0; j < 4; ++j) {
        int col = bCol + wc + j * 16 + l15;
        if (OUT == 0) {
            if (col >= N) continue;
            float bv = bias[col];
#pragma unroll
            for (int i = 0; i < 4; ++i)
#pragma unroll
                for (int r = 0; r < 4; ++r) {
                    int row = bRow + wr + i * 16 + quad * 4 + r;
                    float v = acc[i][j][r] + bv;
                    if (ACT == 1)      v = v > 0.f ? v : 0.f;
                    else if (ACT == 2) v = v >= 0.f ? v : 0.1f * v;
                    else if (ACT == 3) v = tanhf(v);
                    size_t o = (size_t)row * N + col;
                    C0[o] = v;
                    if (C1) C1[o] = v;
                }
        } else {
            if (col >= Kpn) continue;
            const bool real = col < N;
            float bv = real ? bias[col] : 0.f;
#pragma unroll
            for (int i = 0; i < 4; ++i)
#pragma unroll
                for (int r = 0; r < 4; ++r) {
                    int row = bRow + wr + i * 16 + quad * 4 + r;
                    float v = 0.f;
                    if (real) {
                        v = acc[i][j][r] + bv;
                        if (ACT == 1)      v = v > 0.f ? v : 0.f;
                        else if (ACT == 2) v = v >= 0.f ? v : 0.1f * v;
                        else if (ACT == 3) v = tanhf(v);
                    }
                    bf16_t h = (bf16_t)v;
                    bf16_t l = (bf16_t)(v - (float)h);
                    size_t o = (size_t)row * Kpn + col;
                    Phi[o] = h; Plo[o] = l;
                }
        }
    }
}

// np-exact nearest scan (bit-identical to np reference).
__global__ __launch_bounds__(256)
void k_nearest(const float* __restrict__ Q, const float* __restrict__ C,
               const float* __restrict__ q2a, const float* __restrict__ cn2,
               int chunk, float* __restrict__ pd, int* __restrict__ pi)
{
    __shared__ __align__(16) float sc[64][64];
    __shared__ __align__(16) float sn[64];
    const int tid = threadIdx.x;
    const int q   = blockIdx.x * 256 + tid;
    const int G   = gridDim.y;

    float qr[64];
    const float4* qp = (const float4*)(Q + (size_t)q * 64);
#pragma unroll
    for (int i = 0; i < 16; ++i) ((float4*)qr)[i] = qp[i];
    const float q2 = q2a[q];

    float best = 3.4e38f;
    int   bi   = 0x7fffffff;
    const int c0 = blockIdx.y * chunk;

    for (int cb = 0; cb < chunk; cb += 64) {
        __syncthreads();
        const float4* gp = (const float4*)(C + (size_t)(c0 + cb) * 64);
#pragma unroll
        for (int i = 0; i < 4; ++i) {
            int e = tid + i * 256;
            ((float4*)&sc[0][0])[e] = gp[e];
        }
        if (tid < 64) sn[tid] = cn2[c0 + cb + tid];
        __syncthreads();

        for (int c = 0; c < 64; c += 4) {
            float a0 = 0.f, a1 = 0.f, a2 = 0.f, a3 = 0.f;
            const float4* e0 = (const float4*)&sc[c + 0][0];
            const float4* e1 = (const float4*)&sc[c + 1][0];
            const float4* e2p = (const float4*)&sc[c + 2][0];
            const float4* e3 = (const float4*)&sc[c + 3][0];
#pragma unroll
            for (int z = 0; z < 16; ++z) {          // k ascending, chain order exact
                float4 q4 = ((float4*)qr)[z];
                float4 v0 = e0[z], v1 = e1[z], v2 = e2p[z], v3 = e3[z];
                a0 = __fmaf_rn(q4.x, v0.x, a0); a0 = __fmaf_rn(q4.y, v0.y, a0);
                a0 = __fmaf_rn(q4.z, v0.z, a0); a0 = __fmaf_rn(q4.w, v0.w, a0);
                a1 = __fmaf_rn(q4.x, v1.x, a1); a1 = __fmaf_rn(q4.y, v1.y, a1);
                a1 = __fmaf_rn(q4.z, v1.z, a1); a1 = __fmaf_rn(q4.w, v1.w, a1);
                a2 = __fmaf_rn(q4.x, v2.x, a2); a2 = __fmaf_rn(q4.y, v2.y, a2);
                a2 = __fmaf_rn(q4.z, v2.z, a2); a2 = __fmaf_rn(q4.w, v2.w, a2);
                a3 = __fmaf_rn(q4.x, v3.x, a3); a3 = __fmaf_rn(q4.y, v3.y, a3);
                a3 = __fmaf_rn(q4.z, v3.z, a3); a3 = __fmaf_rn(q4.w, v3.w, a3);
            }
            float d;
            d = __fadd_rn(__fsub_rn(q2, __fmul_rn(2.f, a0)), sn[c + 0]);
            if (d < best) { best = d; bi = c0 + cb + c + 0; }
            d = __fadd_rn(__fsub_rn(q2, __fmul_rn(2.f, a1)), sn[c + 1]);
            if (d < best) { best = d; bi = c0 + cb + c + 1; }
            d = __fadd_rn(__fsub_rn(q2, __fmul_rn(2.f, a2)), sn[c + 2]);
            if (d < best) { best = d; bi = c0 + cb + c + 2; }
            d = __fadd_rn(__fsub_rn(q2, __fmul_rn(2.f, a3)), sn[c + 3]);
            if (d < best) { best = d; bi = c0 + cb + c + 3; }
        }
    }
    pd[(size_t)q * G + blockIdx.y] = best;
    pi[(size_t)q * G + blockIdx.y] = bi;
}

__global__ void k_reduce(const float* __restrict__ pd, const int* __restrict__ pi,
                         int G, int NQ, int* __restrict__ out)
{
    int q = blockIdx.x * blockDim.x + threadIdx.x;
    if (q >= NQ) return;
    float best = 3.4e38f; int bi = 0;
    for (int g = 0; g < G; ++g) {
        float d = pd[(size_t)q * G + g];
        if (d < best) { best = d; bi = pi[(size_t)q * G + g]; }
    }
    out[q] = bi;
}

// 256-thread gather: 4 rows/block (launch-count trim vs 64-thread blocks)
__global__ void k_gather(const float* __restrict__ src, const int* __restrict__ idx,
                         float* __restrict__ dst, int nsrc)
{
    int r = blockIdx.x * 4 + (threadIdx.x >> 6), z = threadIdx.x & 63;
    int i = idx[r];
    i = i < 0 ? 0 : (i >= nsrc ? nsrc - 1 : i);
    dst[(size_t)r * 64 + z] = src[(size_t)i * 64 + z];
}

// gather emb rows -> split bf16 planes (decoder layer-1 A input).
__global__ void k_gather_split(const float* __restrict__ src, const int* __restrict__ idx,
                               bf16_t* __restrict__ hi, bf16_t* __restrict__ lo, int nsrc)
{
    int r = blockIdx.x * 4 + (threadIdx.x >> 6), z = threadIdx.x & 63;
    int i = idx[r];
    i = i < 0 ? 0 : (i >= nsrc ? nsrc - 1 : i);
    float v = src[(size_t)i * 64 + z];
    bf16_t h = (bf16_t)v;
    bf16_t l = (bf16_t)(v - (float)h);
    hi[(size_t)r * 64 + z] = h;
    lo[(size_t)r * 64 + z] = l;
}

// numpy pairwise row norm^2 (n=64), bit-exact.
__global__ void k_norm2(const float* __restrict__ s, float* __restrict__ o, int rows)
{
    int r0 = blockIdx.x * blockDim.x + threadIdx.x;
    if (r0 >= rows) return;
    const float* p = s + (size_t)r0 * 64;
    float r[8];
#pragma unroll
    for (int j = 0; j < 8; ++j) r[j] = __fmul_rn(p[j], p[j]);
#pragma unroll
    for (int i = 8; i < 64; i += 8)
#pragma unroll
        for (int j = 0; j < 8; ++j)
            r[j] = __fadd_rn(r[j], __fmul_rn(p[i + j], p[i + j]));
    float t01 = __fadd_rn(r[0], r[1]), t23 = __fadd_rn(r[2], r[3]);
    float t45 = __fadd_rn(r[4], r[5]), t67 = __fadd_rn(r[6], r[7]);
    o[r0] = __fadd_rn(__fadd_rn(t01, t23), __fadd_rn(t45, t67));
}

extern "C" void kernel_launch(void* const* d_in, const int* in_sizes, int n_in,
                              void* d_out, int out_size, void* d_ws, size_t ws_size,
                              hipStream_t stream)
{
    const int B  = 16384;
    const int KC = 4096;

    const float* X   = (const float*)d_in[0];
    const float* We1 = (const float*)d_in[1];
    const float* be1 = (const float*)d_in[2];
    const float* We2 = (const float*)d_in[3];
    const float* be2 = (const float*)d_in[4];
    const float* We3 = (const float*)d_in[5];
    const float* be3 = (const float*)d_in[6];
    const float* We4 = (const float*)d_in[7];
    const float* be4 = (const float*)d_in[8];
    const float* emb = (const float*)d_in[9];
    const float* Wd1 = (const float*)d_in[10];
    const float* bd1 = (const float*)d_in[11];
    const float* Wd2 = (const float*)d_in[12];
    const float* bd2 = (const float*)d_in[13];
    const float* Wd3 = (const float*)d_in[14];
    const float* bd3 = (const float*)d_in[15];
    const float* Wd4 = (const float*)d_in[16];
    const float* bd4 = (const float*)d_in[17];

    float* out = (float*)d_out;
    const size_t OFF1 = (size_t)B * 784;
    const size_t OFF2 = OFF1 + (size_t)B * 64;
    const size_t OFF3 = OFF2 + (size_t)B * 784;
    float* zenc = out + OFF1;

    // dynamic batch tiling (ws_size constant across calls -> graph-safe).
    const size_t FIXED = (size_t)24 << 20;
    int MQ;
    if      (ws_size >= FIXED + (size_t)16384 * 7424) MQ = 16384;
    else if (ws_size >= FIXED + (size_t)8192  * 7424) MQ = 8192;
    else                                              MQ = 4096;
    const int NQn = B / MQ;

    char* ws = (char*)d_ws;
    size_t off = 0;
    auto alloc = [&](size_t bytes) -> void* {
        void* p = ws + off;
        off = (off + bytes + 255) & ~(size_t)255;
        return p;
    };
    float* pd    = (float*)alloc((size_t)262144 * 4);
    int*   pi    = (int*)alloc((size_t)262144 * 4);
    int*   idx1  = (int*)alloc((size_t)B * 4);
    int*   idx2  = (int*)alloc((size_t)KC * 4);
    float* e2    = (float*)alloc((size_t)KC * 4);
    float* z2    = (float*)alloc((size_t)B * 4);
    // encoder padded weights (f32, [NP][KP] zeros)
    float* we1p = (float*)alloc((size_t)1024 * 800 * 4);
    float* we2p = (float*)alloc((size_t)512 * 1024 * 4);
    float* we3p = (float*)alloc((size_t)384 * 512 * 4);
    float* we4p = (float*)alloc((size_t)128 * 320 * 4);
    // decoder split bf16 planes: zemb (full B) + weights
    bf16_t* zembh = (bf16_t*)alloc((size_t)B * 64 * 2);
    bf16_t* zembl = (bf16_t*)alloc((size_t)B * 64 * 2);
    bf16_t* wp1h = (bf16_t*)alloc((size_t)384 * 64 * 2);
    bf16_t* wp1l = (bf16_t*)alloc((size_t)384 * 64 * 2);
    bf16_t* wp2h = (bf16_t*)alloc((size_t)512 * 320 * 2);
    bf16_t* wp2l = (bf16_t*)alloc((size_t)512 * 320 * 2);
    bf16_t* wp3h = (bf16_t*)alloc((size_t)1024 * 512 * 2);
    bf16_t* wp3l = (bf16_t*)alloc((size_t)1024 * 512 * 2);
    bf16_t* wp4h = (bf16_t*)alloc((size_t)896 * 1024 * 2);
    bf16_t* wp4l = (bf16_t*)alloc((size_t)896 * 1024 * 2);
    // big shared region: encoder padded f32 h1..h3, then decoder act planes
    char* big = (char*)alloc((size_t)MQ * 7424);
    float* h1 = (float*)big;                           // MQ x 1024 f32 (N=1000)
    float* h2 = (float*)(big + (size_t)MQ * 4096);     // MQ x 512  (N=500)
    float* h3 = (float*)(big + (size_t)MQ * 6144);     // MQ x 320  (N=300)
    bf16_t* d1h = (bf16_t*)big;                        // MQ x 320 bf16
    bf16_t* d1l = (bf16_t*)(big + (size_t)MQ * 640);
    bf16_t* d2h = (bf16_t*)(big + (size_t)MQ * 1280);  // MQ x 512
    bf16_t* d2l = (bf16_t*)(big + (size_t)MQ * 2304);
    bf16_t* d3h = (bf16_t*)(big + (size_t)MQ * 3328);  // MQ x 1024
    bf16_t* d3l = (bf16_t*)(big + (size_t)MQ * 5376);

    dim3 blk(256);
    // encoder grids: x = row-panels (XCD locality), y = col-blocks (r5 shapes)
    const dim3 eg1(MQ / 128, 8), eg2(MQ / 128, 8), eg3(MQ / 128, 5), eg4(MQ / 128, 1);
    // decoder grids: same axis order
    const dim3 dq1(MQ / 128, 3), dq2(MQ / 128, 4), dq3(MQ / 128, 8), dq4(MQ / 128, 7);

    // ---- fused weight prep (2 kernels instead of 8) ----
    k_padw4 <<<dim3((1581056 + 255) / 256), blk, 0, stream>>>(
        We1, we1p, We2, we2p, We3, we3p, We4, we4p);
    k_split4<<<dim3((1630208 + 255) / 256), blk, 0, stream>>>(
        Wd1, wp1h, wp1l, Wd2, wp2h, wp2l, Wd3, wp3h, wp3l, Wd4, wp4h, wp4l);

    // ---- encoder, np-exact f32 (BLAS-order FMA chains) ----
    for (int q = 0; q < NQn; ++q) {
        const float* Xq = X + (size_t)q * MQ * 784;
        np_gemm<1, 2><<<eg1, blk, 0, stream>>>(Xq, we1p, be1, h1, 1000, 1024, 800, 784, 784);
        np_gemm<1, 1><<<eg2, blk, 0, stream>>>(h1, we2p, be2, h2, 500, 512, 1024, 1024, 1024);
        np_gemm<1, 1><<<eg3, blk, 0, stream>>>(h2, we3p, be3, h3, 300, 320, 512, 512, 512);
        np_gemm<0, 1><<<eg4, blk, 0, stream>>>(h3, we4p, be4,
                                               zenc + (size_t)q * MQ * 64, 64, 64, 320, 320, 320);
    }

    // ---- nearest-neighbor: np-exact, no refine ----
    k_norm2<<<dim3((KC + 255) / 256), blk, 0, stream>>>(emb, e2, KC);
    k_norm2<<<dim3((B + 255) / 256),  blk, 0, stream>>>(zenc, z2, B);

    k_nearest<<<dim3(64, 16), blk, 0, stream>>>(zenc, emb, z2, e2, 256, pd, pi);
    k_reduce <<<dim3(B / 256), blk, 0, stream>>>(pd, pi, 16, B, idx1);
    k_gather_split<<<dim3(B / 4), blk, 0, stream>>>(emb, idx1, zembh, zembl, KC);

    k_nearest<<<dim3(16, 64), blk, 0, stream>>>(emb, zenc, e2, z2, 256, pd, pi);
    k_reduce <<<dim3(KC / 256), blk, 0, stream>>>(pd, pi, 64, KC, idx2);
    k_gather <<<dim3(KC / 4), blk, 0, stream>>>(zenc, idx2, out + OFF3, B);

    // ---- decoder: pre-split planes + global_load_lds MFMA GEMM ----
    for (int q = 0; q < NQn; ++q) {
        gemm_planes<2, 1><<<dq1, blk, 0, stream>>>(
            zembh + (size_t)q * MQ * 64, zembl + (size_t)q * MQ * 64,
            wp1h, wp1l, bd1, nullptr, nullptr, d1h, d1l, 300, 64, 320);
        gemm_planes<2, 1><<<dq2, blk, 0, stream>>>(
            d1h, d1l, wp2h, wp2l, bd2, nullptr, nullptr, d2h, d2l, 500, 320, 512);
        gemm_planes<2, 1><<<dq3, blk, 0, stream>>>(
            d2h, d2l, wp3h, wp3l, bd3, nullptr, nullptr, d3h, d3l, 1000, 512, 1024);
        gemm_planes<3, 0><<<dq4, blk, 0, stream>>>(
            d3h, d3l, wp4h, wp4l, bd4,
            out + (size_t)q * MQ * 784, out + OFF2 + (size_t)q * MQ * 784,
            nullptr, nullptr, 784, 1024, 0);
    }

    (void)in_sizes; (void)n_in; (void)out_size;
}

// Round 10
// 1374.644 us; speedup vs baseline: 1.1756x; 1.0048x over previous
//
#include <hip/hip_runtime.h>
#include <hip/hip_bf16.h>
#include <math.h>

typedef __bf16 bf16_t;
typedef __bf16 bf16x8 __attribute__((ext_vector_type(8)));
typedef __bf16 bf16x4 __attribute__((ext_vector_type(4)));
typedef float f32x4 __attribute__((ext_vector_type(4)));

// async global->LDS, 16B per lane (linear LDS dest = wave base + lane*16)
__device__ __forceinline__ void gload16(const void* g, void* l)
{
    __builtin_amdgcn_global_load_lds(
        (const __attribute__((address_space(1))) void*)g,
        (__attribute__((address_space(3))) void*)l, 16, 0, 0);
}

// ---------------- np-exact f32 GEMM (encoder) ----------------
// Locked structure (r5-r9): k-major LDS tiles, BK=32, gload_lds width-16
// staging with XOR-swizzled global source, 2 barriers/tile, <=32KB LDS,
// 2 blocks/CU. LDS-instruction throughput is the measured wall; reads/FMA:
// CB=2 -> 16/256 = 1/16, CB=1 -> 12/128 = 1/10.7 (1.5x worse). Round 19:
// run L2/L3 at CB=2 (halves their LDS insts per FLOP at unchanged
// occupancy) and L4 at BM=64 (grid 256 -> fills all CUs; was 128 blocks =
// half GPU idle). Kernel body identical to the r7-verified np_gemm4.
// Numerics: per-C-element single-accumulator ascending-k __fmaf_rn chain;
// pad-k FMAs are fma(0,0,acc) exact no-ops.
template<int ACT, int RB, int CB>   // BM = RB*64, BN = CB*64
__global__ __launch_bounds__(256)
void np_gemm4(const float* __restrict__ A, const float* __restrict__ W,
              const float* __restrict__ bias, float* __restrict__ C,
              int N, int Cstride, int KP, int KA, int Kreal)
{
    __shared__ __align__(16) float sA[RB * 64 * 32];
    __shared__ __align__(16) float sB[CB * 64 * 32];
    const int tid = threadIdx.x;
    const int tx  = tid & 15, ty = tid >> 4;
    const int bRow = blockIdx.x * (RB * 64), bCol = blockIdx.y * (CB * 64);

    float acc[RB * 4][CB * 4];
#pragma unroll
    for (int i = 0; i < RB * 4; ++i)
#pragma unroll
        for (int j = 0; j < CB * 4; ++j) acc[i][j] = 0.f;

    const int aswz = ty & 7;   // (arow>>2)&7 == ty&7 (arow = ib*64+ty*4+i)
    const int bswz = tx & 7;   // (brow>>2)&7 == tx&7 (brow = jb*64+tx*4+j)

    for (int k0 = 0; k0 < KP; k0 += 32) {
        __syncthreads();
        if (k0 + 32 <= Kreal) {
            // full tile: pure async copy, source pre-swizzled
#pragma unroll
            for (int i = 0; i < RB * 2; ++i) {
                int L = tid + i * 256;
                int r = L >> 3, cc = L & 7;
                int gc = cc ^ ((r >> 2) & 7);
                gload16(A + (size_t)(bRow + r) * KA + (k0 + gc * 4), sA + L * 4);
            }
        } else {
            // layer-1 K edge (k0=768, Kreal=784): predicated reg staging, zero pad
#pragma unroll
            for (int i = 0; i < RB * 2; ++i) {
                int L = tid + i * 256;
                int r = L >> 3, cc = L & 7;
                int gc = cc ^ ((r >> 2) & 7);
                int gk = k0 + gc * 4;
                float4 v = make_float4(0.f, 0.f, 0.f, 0.f);
                if (gk < Kreal) v = *(const float4*)(A + (size_t)(bRow + r) * KA + gk);
                *(float4*)(sA + L * 4) = v;
            }
        }
#pragma unroll
        for (int i = 0; i < CB * 2; ++i) {
            int L = tid + i * 256;
            int r = L >> 3, cc = L & 7;
            int gc = cc ^ ((r >> 2) & 7);
            gload16(W + (size_t)(bCol + r) * KP + (k0 + gc * 4), sB + L * 4);
        }
        __syncthreads();

#pragma unroll
        for (int kc = 0; kc < 8; ++kc) {       // strictly ascending k
            const int ac = ((kc ^ aswz) << 2);
            const int bc = ((kc ^ bswz) << 2);
            float4 b4[CB][4];
#pragma unroll
            for (int jb = 0; jb < CB; ++jb)
#pragma unroll
                for (int j = 0; j < 4; ++j)
                    b4[jb][j] = *(const float4*)(sB + (jb * 64 + tx * 4 + j) * 32 + bc);
#pragma unroll
            for (int ib = 0; ib < RB; ++ib)
#pragma unroll
                for (int i = 0; i < 4; ++i) {
                    float4 a4 = *(const float4*)(sA + (ib * 64 + ty * 4 + i) * 32 + ac);
#pragma unroll
                    for (int jb = 0; jb < CB; ++jb)
#pragma unroll
                        for (int j = 0; j < 4; ++j) {
                            float& o = acc[ib * 4 + i][jb * 4 + j];
                            o = __fmaf_rn(a4.x, b4[jb][j].x, o);
                            o = __fmaf_rn(a4.y, b4[jb][j].y, o);
                            o = __fmaf_rn(a4.z, b4[jb][j].z, o);
                            o = __fmaf_rn(a4.w, b4[jb][j].w, o);
                        }
                }
        }
    }

#pragma unroll
    for (int jb = 0; jb < CB; ++jb) {
        int col4 = bCol + jb * 64 + tx * 4;
        if (col4 >= Cstride) continue;     // Cstride%4==0 -> whole float4 ok
#pragma unroll
        for (int ib = 0; ib < RB; ++ib)
#pragma unroll
            for (int i = 0; i < 4; ++i) {
                int row = bRow + ib * 64 + ty * 4 + i;
                float ov[4];
#pragma unroll
                for (int j = 0; j < 4; ++j) {
                    int col = col4 + j;
                    float v = 0.f;
                    if (col < N) {
                        v = __fadd_rn(acc[ib * 4 + i][jb * 4 + j], bias[col]);
                        if (ACT == 1) v = v > 0.f ? v : 0.f;
                    }
                    ov[j] = v;
                }
                *(float4*)(C + (size_t)row * Cstride + col4) =
                    make_float4(ov[0], ov[1], ov[2], ov[3]);
            }
    }
}

// ---- fused weight prep: all 4 encoder pads in ONE kernel (launch trim) ----
__global__ void k_padw4(const float* s0, float* d0, const float* s1, float* d1,
                        const float* s2, float* d2, const float* s3, float* d3)
{
    // 0: 1024x800  1: 512x1024  2: 384x512  3: 128x320
    int e = blockIdx.x * 256 + threadIdx.x;
    const float* src; float* dst; int rows, K, Kp;
    if (e < 819200)        { src=s0; dst=d0; rows=1000; K=784;  Kp=800;  }
    else if (e < 1343488)  { e -= 819200;  src=s1; dst=d1; rows=500;  K=1000; Kp=1024; }
    else if (e < 1540096)  { e -= 1343488; src=s2; dst=d2; rows=300;  K=500;  Kp=512;  }
    else if (e < 1581056)  { e -= 1540096; src=s3; dst=d3; rows=64;   K=300;  Kp=320;  }
    else return;
    int r = e / Kp, k = e - r * Kp;
    dst[e] = (r < rows && k < K) ? src[(size_t)r * K + k] : 0.f;
}

// ---- fused weight split: all 4 decoder splits in ONE kernel ----
__global__ void k_split4(const float* s0, bf16_t* h0, bf16_t* l0,
                         const float* s1, bf16_t* h1, bf16_t* l1,
                         const float* s2, bf16_t* h2, bf16_t* l2,
                         const float* s3, bf16_t* h3, bf16_t* l3)
{
    // 0: 384x64  1: 512x320  2: 1024x512  3: 896x1024
    int e = blockIdx.x * 256 + threadIdx.x;
    const float* src; bf16_t* hi; bf16_t* lo; int rows, K, Kp;
    if (e < 24576)         { src=s0; hi=h0; lo=l0; rows=300;  K=64;   Kp=64;   }
    else if (e < 188416)   { e -= 24576;  src=s1; hi=h1; lo=l1; rows=500;  K=300;  Kp=320;  }
    else if (e < 712704)   { e -= 188416; src=s2; hi=h2; lo=l2; rows=1000; K=500;  Kp=512;  }
    else if (e < 1630208)  { e -= 712704; src=s3; hi=h3; lo=l3; rows=784;  K=1000; Kp=1024; }
    else return;
    int r = e / Kp, k = e - r * Kp;
    float v = (r < rows && k < K) ? src[(size_t)r * K + k] : 0.f;
    bf16_t h = (bf16_t)v;
    bf16_t l = (bf16_t)(v - (float)h);
    hi[e] = h; lo[e] = l;
}

// ---------------- bf16 MFMA GEMM on pre-split planes (decoder) ------------
template<int ACT, int OUT>
__global__ __launch_bounds__(256)
void gemm_planes(const bf16_t* __restrict__ Ahi, const bf16_t* __restrict__ Alo,
                 const bf16_t* __restrict__ Bhi, const bf16_t* __restrict__ Blo,
                 const float* __restrict__ bias,
                 float* __restrict__ C0, float* __restrict__ C1,
                 bf16_t* __restrict__ Phi, bf16_t* __restrict__ Plo,
                 int N, int Kp, int Kpn)
{
    __shared__ __align__(16) bf16_t sA[2][128][32];
    __shared__ __align__(16) bf16_t sB[2][128][32];

    const int tid  = threadIdx.x;
    const int bRow = blockIdx.x * 128;
    const int bCol = blockIdx.y * 128;
    const int wave = tid >> 6;
    const int lane = tid & 63;
    const int wr   = (wave >> 1) * 64;
    const int wc   = (wave & 1) * 64;
    const int quad = lane >> 4;
    const int l15  = lane & 15;

    f32x4 acc[4][4];
#pragma unroll
    for (int i = 0; i < 4; ++i)
#pragma unroll
        for (int j = 0; j < 4; ++j) acc[i][j] = (f32x4){0.f, 0.f, 0.f, 0.f};

    for (int k0 = 0; k0 < Kp; k0 += 32) {
        __syncthreads();
#pragma unroll
        for (int i = 0; i < 2; ++i) {
            int c    = tid + i * 256;
            int row  = c >> 2;
            int koff = (c & 3) << 3;
            size_t ga = (size_t)(bRow + row) * Kp + (k0 + koff);
            size_t gb = (size_t)(bCol + row) * Kp + (k0 + koff);
            gload16(Ahi + ga, &sA[0][row][koff]);
            gload16(Alo + ga, &sA[1][row][koff]);
            gload16(Bhi + gb, &sB[0][row][koff]);
            gload16(Blo + gb, &sB[1][row][koff]);
        }
        __syncthreads();

        bf16x8 af[2][4], bfr[2][4];
#pragma unroll
        for (int t = 0; t < 2; ++t)
#pragma unroll
            for (int i = 0; i < 4; ++i) {
                af[t][i]  = *(const bf16x8*)&sA[t][wr + i * 16 + l15][quad * 8];
                bfr[t][i] = *(const bf16x8*)&sB[t][wc + i * 16 + l15][quad * 8];
            }
#pragma unroll
        for (int i = 0; i < 4; ++i)
#pragma unroll
            for (int j = 0; j < 4; ++j)
#pragma unroll
                for (int ta = 0; ta < 2; ++ta)
#pragma unroll
                    for (int tb = 0; tb < 2 - ta; ++tb)
                        acc[i][j] = __builtin_amdgcn_mfma_f32_16x16x32_bf16(
                            af[ta][i], bfr[tb][j], acc[i][j], 0, 0, 0);
    }

#pragma unroll
    for (int j = 0; j < 4; ++j) {
        int col = bCol + wc + j * 16 + l15;
        if (OUT == 0) {
            if (col >= N) continue;
            float bv = bias[col];
#pragma unroll
            for (int i = 0; i < 4; ++i)
#pragma unroll
                for (int r = 0; r < 4; ++r) {
                    int row = bRow + wr + i * 16 + quad * 4 + r;
                    float v = acc[i][j][r] + bv;
                    if (ACT == 1)      v = v > 0.f ? v : 0.f;
                    else if (ACT == 2) v = v >= 0.f ? v : 0.1f * v;
                    else if (ACT == 3) v = tanhf(v);
                    size_t o = (size_t)row * N + col;
                    C0[o] = v;
                    if (C1) C1[o] = v;
                }
        } else {
            if (col >= Kpn) continue;
            const bool real = col < N;
            float bv = real ? bias[col] : 0.f;
#pragma unroll
            for (int i = 0; i < 4; ++i)
#pragma unroll
                for (int r = 0; r < 4; ++r) {
                    int row = bRow + wr + i * 16 + quad * 4 + r;
                    float v = 0.f;
                    if (real) {
                        v = acc[i][j][r] + bv;
                        if (ACT == 1)      v = v > 0.f ? v : 0.f;
                        else if (ACT == 2) v = v >= 0.f ? v : 0.1f * v;
                        else if (ACT == 3) v = tanhf(v);
                    }
                    bf16_t h = (bf16_t)v;
                    bf16_t l = (bf16_t)(v - (float)h);
                    size_t o = (size_t)row * Kpn + col;
                    Phi[o] = h; Plo[o] = l;
                }
        }
    }
}

// np-exact nearest scan (bit-identical to np reference).
__global__ __launch_bounds__(256)
void k_nearest(const float* __restrict__ Q, const float* __restrict__ C,
               const float* __restrict__ q2a, const float* __restrict__ cn2,
               int chunk, float* __restrict__ pd, int* __restrict__ pi)
{
    __shared__ __align__(16) float sc[64][64];
    __shared__ __align__(16) float sn[64];
    const int tid = threadIdx.x;
    const int q   = blockIdx.x * 256 + tid;
    const int G   = gridDim.y;

    float qr[64];
    const float4* qp = (const float4*)(Q + (size_t)q * 64);
#pragma unroll
    for (int i = 0; i < 16; ++i) ((float4*)qr)[i] = qp[i];
    const float q2 = q2a[q];

    float best = 3.4e38f;
    int   bi   = 0x7fffffff;
    const int c0 = blockIdx.y * chunk;

    for (int cb = 0; cb < chunk; cb += 64) {
        __syncthreads();
        const float4* gp = (const float4*)(C + (size_t)(c0 + cb) * 64);
#pragma unroll
        for (int i = 0; i < 4; ++i) {
            int e = tid + i * 256;
            ((float4*)&sc[0][0])[e] = gp[e];
        }
        if (tid < 64) sn[tid] = cn2[c0 + cb + tid];
        __syncthreads();

        for (int c = 0; c < 64; c += 4) {
            float a0 = 0.f, a1 = 0.f, a2 = 0.f, a3 = 0.f;
            const float4* e0 = (const float4*)&sc[c + 0][0];
            const float4* e1 = (const float4*)&sc[c + 1][0];
            const float4* e2p = (const float4*)&sc[c + 2][0];
            const float4* e3 = (const float4*)&sc[c + 3][0];
#pragma unroll
            for (int z = 0; z < 16; ++z) {          // k ascending, chain order exact
                float4 q4 = ((float4*)qr)[z];
                float4 v0 = e0[z], v1 = e1[z], v2 = e2p[z], v3 = e3[z];
                a0 = __fmaf_rn(q4.x, v0.x, a0); a0 = __fmaf_rn(q4.y, v0.y, a0);
                a0 = __fmaf_rn(q4.z, v0.z, a0); a0 = __fmaf_rn(q4.w, v0.w, a0);
                a1 = __fmaf_rn(q4.x, v1.x, a1); a1 = __fmaf_rn(q4.y, v1.y, a1);
                a1 = __fmaf_rn(q4.z, v1.z, a1); a1 = __fmaf_rn(q4.w, v1.w, a1);
                a2 = __fmaf_rn(q4.x, v2.x, a2); a2 = __fmaf_rn(q4.y, v2.y, a2);
                a2 = __fmaf_rn(q4.z, v2.z, a2); a2 = __fmaf_rn(q4.w, v2.w, a2);
                a3 = __fmaf_rn(q4.x, v3.x, a3); a3 = __fmaf_rn(q4.y, v3.y, a3);
                a3 = __fmaf_rn(q4.z, v3.z, a3); a3 = __fmaf_rn(q4.w, v3.w, a3);
            }
            float d;
            d = __fadd_rn(__fsub_rn(q2, __fmul_rn(2.f, a0)), sn[c + 0]);
            if (d < best) { best = d; bi = c0 + cb + c + 0; }
            d = __fadd_rn(__fsub_rn(q2, __fmul_rn(2.f, a1)), sn[c + 1]);
            if (d < best) { best = d; bi = c0 + cb + c + 1; }
            d = __fadd_rn(__fsub_rn(q2, __fmul_rn(2.f, a2)), sn[c + 2]);
            if (d < best) { best = d; bi = c0 + cb + c + 2; }
            d = __fadd_rn(__fsub_rn(q2, __fmul_rn(2.f, a3)), sn[c + 3]);
            if (d < best) { best = d; bi = c0 + cb + c + 3; }
        }
    }
    pd[(size_t)q * G + blockIdx.y] = best;
    pi[(size_t)q * G + blockIdx.y] = bi;
}

__global__ void k_reduce(const float* __restrict__ pd, const int* __restrict__ pi,
                         int G, int NQ, int* __restrict__ out)
{
    int q = blockIdx.x * blockDim.x + threadIdx.x;
    if (q >= NQ) return;
    float best = 3.4e38f; int bi = 0;
    for (int g = 0; g < G; ++g) {
        float d = pd[(size_t)q * G + g];
        if (d < best) { best = d; bi = pi[(size_t)q * G + g]; }
    }
    out[q] = bi;
}

// 256-thread gather: 4 rows/block
__global__ void k_gather(const float* __restrict__ src, const int* __restrict__ idx,
                         float* __restrict__ dst, int nsrc)
{
    int r = blockIdx.x * 4 + (threadIdx.x >> 6), z = threadIdx.x & 63;
    int i = idx[r];
    i = i < 0 ? 0 : (i >= nsrc ? nsrc - 1 : i);
    dst[(size_t)r * 64 + z] = src[(size_t)i * 64 + z];
}

// gather emb rows -> split bf16 planes (decoder layer-1 A input).
__global__ void k_gather_split(const float* __restrict__ src, const int* __restrict__ idx,
                               bf16_t* __restrict__ hi, bf16_t* __restrict__ lo, int nsrc)
{
    int r = blockIdx.x * 4 + (threadIdx.x >> 6), z = threadIdx.x & 63;
    int i = idx[r];
    i = i < 0 ? 0 : (i >= nsrc ? nsrc - 1 : i);
    float v = src[(size_t)i * 64 + z];
    bf16_t h = (bf16_t)v;
    bf16_t l = (bf16_t)(v - (float)h);
    hi[(size_t)r * 64 + z] = h;
    lo[(size_t)r * 64 + z] = l;
}

// numpy pairwise row norm^2 (n=64), bit-exact.
__global__ void k_norm2(const float* __restrict__ s, float* __restrict__ o, int rows)
{
    int r0 = blockIdx.x * blockDim.x + threadIdx.x;
    if (r0 >= rows) return;
    const float* p = s + (size_t)r0 * 64;
    float r[8];
#pragma unroll
    for (int j = 0; j < 8; ++j) r[j] = __fmul_rn(p[j], p[j]);
#pragma unroll
    for (int i = 8; i < 64; i += 8)
#pragma unroll
        for (int j = 0; j < 8; ++j)
            r[j] = __fadd_rn(r[j], __fmul_rn(p[i + j], p[i + j]));
    float t01 = __fadd_rn(r[0], r[1]), t23 = __fadd_rn(r[2], r[3]);
    float t45 = __fadd_rn(r[4], r[5]), t67 = __fadd_rn(r[6], r[7]);
    o[r0] = __fadd_rn(__fadd_rn(t01, t23), __fadd_rn(t45, t67));
}

extern "C" void kernel_launch(void* const* d_in, const int* in_sizes, int n_in,
                              void* d_out, int out_size, void* d_ws, size_t ws_size,
                              hipStream_t stream)
{
    const int B  = 16384;
    const int KC = 4096;

    const float* X   = (const float*)d_in[0];
    const float* We1 = (const float*)d_in[1];
    const float* be1 = (const float*)d_in[2];
    const float* We2 = (const float*)d_in[3];
    const float* be2 = (const float*)d_in[4];
    const float* We3 = (const float*)d_in[5];
    const float* be3 = (const float*)d_in[6];
    const float* We4 = (const float*)d_in[7];
    const float* be4 = (const float*)d_in[8];
    const float* emb = (const float*)d_in[9];
    const float* Wd1 = (const float*)d_in[10];
    const float* bd1 = (const float*)d_in[11];
    const float* Wd2 = (const float*)d_in[12];
    const float* bd2 = (const float*)d_in[13];
    const float* Wd3 = (const float*)d_in[14];
    const float* bd3 = (const float*)d_in[15];
    const float* Wd4 = (const float*)d_in[16];
    const float* bd4 = (const float*)d_in[17];

    float* out = (float*)d_out;
    const size_t OFF1 = (size_t)B * 784;
    const size_t OFF2 = OFF1 + (size_t)B * 64;
    const size_t OFF3 = OFF2 + (size_t)B * 784;
    float* zenc = out + OFF1;

    // dynamic batch tiling (ws_size constant across calls -> graph-safe).
    const size_t FIXED = (size_t)24 << 20;
    int MQ;
    if      (ws_size >= FIXED + (size_t)16384 * 7424) MQ = 16384;
    else if (ws_size >= FIXED + (size_t)8192  * 7424) MQ = 8192;
    else                                              MQ = 4096;
    const int NQn = B / MQ;

    char* ws = (char*)d_ws;
    size_t off = 0;
    auto alloc = [&](size_t bytes) -> void* {
        void* p = ws + off;
        off = (off + bytes + 255) & ~(size_t)255;
        return p;
    };
    float* pd    = (float*)alloc((size_t)262144 * 4);
    int*   pi    = (int*)alloc((size_t)262144 * 4);
    int*   idx1  = (int*)alloc((size_t)B * 4);
    int*   idx2  = (int*)alloc((size_t)KC * 4);
    float* e2    = (float*)alloc((size_t)KC * 4);
    float* z2    = (float*)alloc((size_t)B * 4);
    // encoder padded weights (f32, [NP][KP] zeros)
    float* we1p = (float*)alloc((size_t)1024 * 800 * 4);
    float* we2p = (float*)alloc((size_t)512 * 1024 * 4);
    float* we3p = (float*)alloc((size_t)384 * 512 * 4);
    float* we4p = (float*)alloc((size_t)128 * 320 * 4);
    // decoder split bf16 planes: zemb (full B) + weights
    bf16_t* zembh = (bf16_t*)alloc((size_t)B * 64 * 2);
    bf16_t* zembl = (bf16_t*)alloc((size_t)B * 64 * 2);
    bf16_t* wp1h = (bf16_t*)alloc((size_t)384 * 64 * 2);
    bf16_t* wp1l = (bf16_t*)alloc((size_t)384 * 64 * 2);
    bf16_t* wp2h = (bf16_t*)alloc((size_t)512 * 320 * 2);
    bf16_t* wp2l = (bf16_t*)alloc((size_t)512 * 320 * 2);
    bf16_t* wp3h = (bf16_t*)alloc((size_t)1024 * 512 * 2);
    bf16_t* wp3l = (bf16_t*)alloc((size_t)1024 * 512 * 2);
    bf16_t* wp4h = (bf16_t*)alloc((size_t)896 * 1024 * 2);
    bf16_t* wp4l = (bf16_t*)alloc((size_t)896 * 1024 * 2);
    // big shared region: encoder padded f32 h1..h3, then decoder act planes
    char* big = (char*)alloc((size_t)MQ * 7424);
    float* h1 = (float*)big;                           // MQ x 1024 f32 (N=1000)
    float* h2 = (float*)(big + (size_t)MQ * 4096);     // MQ x 512  (N=500)
    float* h3 = (float*)(big + (size_t)MQ * 6144);     // MQ x 320  (N=300)
    bf16_t* d1h = (bf16_t*)big;                        // MQ x 320 bf16
    bf16_t* d1l = (bf16_t*)(big + (size_t)MQ * 640);
    bf16_t* d2h = (bf16_t*)(big + (size_t)MQ * 1280);  // MQ x 512
    bf16_t* d2l = (bf16_t*)(big + (size_t)MQ * 2304);
    bf16_t* d3h = (bf16_t*)(big + (size_t)MQ * 3328);  // MQ x 1024
    bf16_t* d3l = (bf16_t*)(big + (size_t)MQ * 5376);

    dim3 blk(256);
    // encoder grids: x = row-panels (XCD locality), y = col-blocks.
    // L1 RB2/CB2 y=8; L2 RB2/CB2 y=4 (was CB1 y=8: 1.5x more LDS/FMA);
    // L3 RB2/CB2 y=3; L4 RB1/CB1 grid 256 (was 128: half GPU idle).
    const dim3 eg1(MQ / 128, 8), eg2(MQ / 128, 4), eg3(MQ / 128, 3), eg4(MQ / 64, 1);
    // decoder grids: same axis order
    const dim3 dq1(MQ / 128, 3), dq2(MQ / 128, 4), dq3(MQ / 128, 8), dq4(MQ / 128, 7);

    // ---- fused weight prep (2 kernels) ----
    k_padw4 <<<dim3((1581056 + 255) / 256), blk, 0, stream>>>(
        We1, we1p, We2, we2p, We3, we3p, We4, we4p);
    k_split4<<<dim3((1630208 + 255) / 256), blk, 0, stream>>>(
        Wd1, wp1h, wp1l, Wd2, wp2h, wp2l, Wd3, wp3h, wp3l, Wd4, wp4h, wp4l);

    // ---- encoder, np-exact f32 (BLAS-order FMA chains) ----
    for (int q = 0; q < NQn; ++q) {
        const float* Xq = X + (size_t)q * MQ * 784;
        np_gemm4<1, 2, 2><<<eg1, blk, 0, stream>>>(Xq, we1p, be1, h1, 1000, 1024, 800, 784, 784);
        np_gemm4<1, 2, 2><<<eg2, blk, 0, stream>>>(h1, we2p, be2, h2, 500, 512, 1024, 1024, 1024);
        np_gemm4<1, 2, 2><<<eg3, blk, 0, stream>>>(h2, we3p, be3, h3, 300, 320, 512, 512, 512);
        np_gemm4<0, 1, 1><<<eg4, blk, 0, stream>>>(h3, we4p, be4,
                                                   zenc + (size_t)q * MQ * 64, 64, 64, 320, 320, 320);
    }

    // ---- nearest-neighbor: np-exact, no refine ----
    k_norm2<<<dim3((KC + 255) / 256), blk, 0, stream>>>(emb, e2, KC);
    k_norm2<<<dim3((B + 255) / 256),  blk, 0, stream>>>(zenc, z2, B);

    k_nearest<<<dim3(64, 16), blk, 0, stream>>>(zenc, emb, z2, e2, 256, pd, pi);
    k_reduce <<<dim3(B / 256), blk, 0, stream>>>(pd, pi, 16, B, idx1);
    k_gather_split<<<dim3(B / 4), blk, 0, stream>>>(emb, idx1, zembh, zembl, KC);

    k_nearest<<<dim3(16, 64), blk, 0, stream>>>(emb, zenc, e2, z2, 256, pd, pi);
    k_reduce <<<dim3(KC / 256), blk, 0, stream>>>(pd, pi, 64, KC, idx2);
    k_gather <<<dim3(KC / 4), blk, 0, stream>>>(zenc, idx2, out + OFF3, B);

    // ---- decoder: pre-split planes + global_load_lds MFMA GEMM ----
    for (int q = 0; q < NQn; ++q) {
        gemm_planes<2, 1><<<dq1, blk, 0, stream>>>(
            zembh + (size_t)q * MQ * 64, zembl + (size_t)q * MQ * 64,
            wp1h, wp1l, bd1, nullptr, nullptr, d1h, d1l, 300, 64, 320);
        gemm_planes<2, 1><<<dq2, blk, 0, stream>>>(
            d1h, d1l, wp2h, wp2l, bd2, nullptr, nullptr, d2h, d2l, 500, 320, 512);
        gemm_planes<2, 1><<<dq3, blk, 0, stream>>>(
            d2h, d2l, wp3h, wp3l, bd3, nullptr, nullptr, d3h, d3l, 1000, 512, 1024);
        gemm_planes<3, 0><<<dq4, blk, 0, stream>>>(
            d3h, d3l, wp4h, wp4l, bd4,
            out + (size_t)q * MQ * 784, out + OFF2 + (size_t)q * MQ * 784,
            nullptr, nullptr, 784, 1024, 0);
    }

    (void)in_sizes; (void)n_in; (void)out_size;
}